// Round 1
// baseline (20073.112 us; speedup 1.0000x reference)
//
#include <hip/hip_runtime.h>

#define NPTS 4096
#define NB 8
#define KNN 20
#define CNT1f 655360.0f   // B*N*K
#define CNT3f 32768.0f    // B*N
#define BNEPS 1e-5f

// ---- workspace layout (float offsets into d_ws) ----
#define OFF_IDX   0              // int[655360]
#define OFF_M     655360         // float[8*4096*128] pooled conv2 features
#define OFF_ACC0  4849664        // start of zeroed accumulator region
#define OFF_SUM1P 4849664        // [8][64]
#define OFF_SSQ1P 4850176
#define OFF_SUM2P 4850688        // [8][128]
#define OFF_SSQ2P 4851712
#define OFF_SUM3  4852736        // [1024]
#define OFF_SSQ3  4853760
#define OFF_GMAX  4854784        // [8][1024] float bits via atomicMax(uint)
#define N_ZERO    13312
#define OFF_SC1   4862976
#define OFF_SH1   4863040
#define OFF_SC2   4863104
#define OFF_SH2   4863232
#define OFF_SC3   4863360
#define OFF_SH3   4864384
#define OFF_Z4    4865408        // [8][512]
// total ≈ 4869504 floats ≈ 18.6 MB

__global__ __launch_bounds__(256) void k_init(float* W) {
    int i = blockIdx.x * 256 + threadIdx.x;   // grid 52*256 == 13312 exactly
    W[OFF_ACC0 + i] = 0.0f;
}

// ---------------- KNN: one thread per query, all points in LDS ----------------
__global__ __launch_bounds__(256) void k_knn(const float* __restrict__ x, int* __restrict__ idx) {
    __shared__ float px[NPTS], py[NPTS], pz[NPTS];   // 48 KB
    const int b = blockIdx.y;
    const float* xb = x + b * 3 * NPTS;
    for (int i = threadIdx.x; i < NPTS; i += 256) {
        px[i] = xb[i]; py[i] = xb[NPTS + i]; pz[i] = xb[2 * NPTS + i];
    }
    __syncthreads();
    const int q = blockIdx.x * 256 + threadIdx.x;
    const float qx = px[q], qy = py[q], qz = pz[q];
    float bv[KNN]; int bi[KNN];
#pragma unroll
    for (int t = 0; t < KNN; ++t) { bv[t] = -3.0e38f; bi[t] = 0; }
    for (int j = 0; j < NPTS; ++j) {
        float dx = px[j] - qx, dy = py[j] - qy, dz = pz[j] - qz;
        float d = -(dx * dx + dy * dy + dz * dz);
        if (d > bv[KNN - 1]) {
            bv[KNN - 1] = d; bi[KNN - 1] = j;
#pragma unroll
            for (int p = KNN - 1; p > 0; --p) {
                if (bv[p] > bv[p - 1]) {
                    float tv = bv[p]; bv[p] = bv[p - 1]; bv[p - 1] = tv;
                    int ti = bi[p]; bi[p] = bi[p - 1]; bi[p - 1] = ti;
                }
            }
        }
    }
    const int base = (b * NPTS + q) * KNN;
#pragma unroll
    for (int t = 0; t < KNN; ++t) idx[base + t] = bi[t];
}

// ---------------- conv1 stats: z1 = w1·edge, accumulate sum/sumsq -------------
__global__ __launch_bounds__(256) void k_c1stats(const float* __restrict__ x, const int* __restrict__ idx,
                                                 const float* __restrict__ w1, float* W) {
    __shared__ float eds[320 * 6];
    __shared__ float w1s[64 * 6];
    __shared__ float red[256];
    const int b = blockIdx.y, q0 = blockIdx.x * 16;
    const float* xb = x + b * 3 * NPTS;
    for (int i = threadIdx.x; i < 384; i += 256) w1s[i] = w1[i];
    const int ebase = (b * NPTS + q0) * KNN;
    for (int e = threadIdx.x; e < 320; e += 256) {
        int q = q0 + e / KNN;
        int j = idx[ebase + e];
        float cx = xb[q], cy = xb[NPTS + q], cz = xb[2 * NPTS + q];
        float* E = &eds[e * 6];
        E[0] = cx; E[1] = cy; E[2] = cz;
        E[3] = xb[j] - cx; E[4] = xb[NPTS + j] - cy; E[5] = xb[2 * NPTS + j] - cz;
    }
    __syncthreads();
    const int c = threadIdx.x & 63, g = threadIdx.x >> 6;
    const float* wr = &w1s[c * 6];
    float v0 = wr[0], v1 = wr[1], v2 = wr[2], v3 = wr[3], v4 = wr[4], v5 = wr[5];
    float s = 0.f, s2 = 0.f;
    for (int e = g; e < 320; e += 4) {
        const float* E = &eds[e * 6];
        float z = v0 * E[0] + v1 * E[1] + v2 * E[2] + v3 * E[3] + v4 * E[4] + v5 * E[5];
        s += z; s2 += z * z;
    }
    const int part = blockIdx.x & 7;
    red[threadIdx.x] = s; __syncthreads();
    if (g == 0) atomicAdd(&W[OFF_SUM1P + part * 64 + c], red[c] + red[64 + c] + red[128 + c] + red[192 + c]);
    __syncthreads();
    red[threadIdx.x] = s2; __syncthreads();
    if (g == 0) atomicAdd(&W[OFF_SSQ1P + part * 64 + c], red[c] + red[64 + c] + red[128 + c] + red[192 + c]);
}

__global__ void k_fin1(const float* __restrict__ g1, const float* __restrict__ b1, float* W) {
    int c = threadIdx.x;
    if (c < 64) {
        float s = 0, q = 0;
        for (int p = 0; p < 8; ++p) { s += W[OFF_SUM1P + p * 64 + c]; q += W[OFF_SSQ1P + p * 64 + c]; }
        float mean = s * (1.f / CNT1f);
        float var = q * (1.f / CNT1f) - mean * mean;
        float sc = g1[c] * rsqrtf(var + BNEPS);
        W[OFF_SC1 + c] = sc;
        W[OFF_SH1 + c] = b1[c] - mean * sc;
    }
}

// ---- conv2 shared preamble: edges -> h1 (post bn1+relu) in LDS, w2 transposed
__device__ __forceinline__ void c2_prepare(const float* xb, const int* __restrict__ idx, int ebase, int q0,
                                           const float* __restrict__ w1, const float* __restrict__ w2,
                                           const float* W, float* eds, float* h1s, float* w2t) {
    const int t = threadIdx.x;
    for (int i = t; i < 8192; i += 256) {        // w2t[j*132 + c] = w2[c*64 + j]
        int c = i >> 6, j = i & 63;
        w2t[j * 132 + c] = w2[i];
    }
    if (t < 80) {
        int q = q0 + t / KNN;
        int j = idx[ebase + t];
        float cx = xb[q], cy = xb[NPTS + q], cz = xb[2 * NPTS + q];
        float* E = &eds[t * 6];
        E[0] = cx; E[1] = cy; E[2] = cz;
        E[3] = xb[j] - cx; E[4] = xb[NPTS + j] - cy; E[5] = xb[2 * NPTS + j] - cz;
    }
    __syncthreads();
    const int c = t & 63, g = t >> 6;
    const float sc = W[OFF_SC1 + c], sh = W[OFF_SH1 + c];
    const float* wr = &w1[c * 6];
    float v0 = wr[0], v1 = wr[1], v2 = wr[2], v3 = wr[3], v4 = wr[4], v5 = wr[5];
    for (int e = g; e < 80; e += 4) {
        const float* E = &eds[e * 6];
        float z = v0 * E[0] + v1 * E[1] + v2 * E[2] + v3 * E[3] + v4 * E[4] + v5 * E[5];
        float h = sc * z + sh;
        h1s[e * 64 + c] = h > 0.f ? h : 0.f;
    }
    __syncthreads();
}

__global__ __launch_bounds__(256) void k_c2stats(const float* __restrict__ x, const int* __restrict__ idxp,
                                                 const float* __restrict__ w1, const float* __restrict__ w2,
                                                 float* W) {
    __shared__ float eds[80 * 6];
    __shared__ float h1s[80 * 64];
    __shared__ float w2t[64 * 132];
    __shared__ float red[512];
    const int b = blockIdx.y, q0 = blockIdx.x * 4;
    const float* xb = x + b * 3 * NPTS;
    c2_prepare(xb, idxp, (b * NPTS + q0) * KNN, q0, w1, w2, W, eds, h1s, w2t);
    const int cg = threadIdx.x & 31, eg = threadIdx.x >> 5;
    float sa[4] = {0, 0, 0, 0}, qa[4] = {0, 0, 0, 0};
    for (int it = 0; it < 5; ++it) {
        int e = 2 * eg + 16 * it;
        float za[4] = {0, 0, 0, 0}, zb[4] = {0, 0, 0, 0};
        const float* h0 = &h1s[e * 64];
        const float* h1 = &h1s[e * 64 + 64];
        for (int j = 0; j < 64; ++j) {
            float4 wv = *(const float4*)&w2t[j * 132 + 4 * cg];
            float a = h0[j], bb = h1[j];
            za[0] += wv.x * a; za[1] += wv.y * a; za[2] += wv.z * a; za[3] += wv.w * a;
            zb[0] += wv.x * bb; zb[1] += wv.y * bb; zb[2] += wv.z * bb; zb[3] += wv.w * bb;
        }
#pragma unroll
        for (int c = 0; c < 4; ++c) {
            sa[c] += za[c] + zb[c];
            qa[c] += za[c] * za[c] + zb[c] * zb[c];
        }
    }
    const int part = blockIdx.x & 7;
    for (int c = 0; c < 4; ++c) {
        __syncthreads();
        red[threadIdx.x] = sa[c]; red[256 + threadIdx.x] = qa[c];
        __syncthreads();
        if (threadIdx.x < 32) {
            float ts = 0, tq = 0;
            for (int g = 0; g < 8; ++g) { ts += red[g * 32 + threadIdx.x]; tq += red[256 + g * 32 + threadIdx.x]; }
            atomicAdd(&W[OFF_SUM2P + part * 128 + 4 * threadIdx.x + c], ts);
            atomicAdd(&W[OFF_SSQ2P + part * 128 + 4 * threadIdx.x + c], tq);
        }
    }
}

__global__ void k_fin2(const float* __restrict__ g2, const float* __restrict__ b2, float* W) {
    int c = threadIdx.x;
    if (c < 128) {
        float s = 0, q = 0;
        for (int p = 0; p < 8; ++p) { s += W[OFF_SUM2P + p * 128 + c]; q += W[OFF_SSQ2P + p * 128 + c]; }
        float mean = s * (1.f / CNT1f);
        float var = q * (1.f / CNT1f) - mean * mean;
        float sc = g2[c] * rsqrtf(var + BNEPS);
        W[OFF_SC2 + c] = sc;
        W[OFF_SH2 + c] = b2[c] - mean * sc;
    }
}

__global__ __launch_bounds__(256) void k_c2apply(const float* __restrict__ x, const int* __restrict__ idxp,
                                                 const float* __restrict__ w1, const float* __restrict__ w2,
                                                 float* W) {
    __shared__ float eds[80 * 6];
    __shared__ float h1s[80 * 64];
    __shared__ float w2t[64 * 132];
    const int b = blockIdx.y, q0 = blockIdx.x * 4;
    const float* xb = x + b * 3 * NPTS;
    c2_prepare(xb, idxp, (b * NPTS + q0) * KNN, q0, w1, w2, W, eds, h1s, w2t);
    const int cg = threadIdx.x & 31, qg = threadIdx.x >> 5;
    const int q = qg >> 1, kh = qg & 1;
    float sc[4], sh[4], mx[4] = {0.f, 0.f, 0.f, 0.f};
#pragma unroll
    for (int c = 0; c < 4; ++c) { sc[c] = W[OFF_SC2 + 4 * cg + c]; sh[c] = W[OFF_SH2 + 4 * cg + c]; }
    for (int kk = 0; kk < 5; ++kk) {
        int e = q * 20 + kh * 10 + 2 * kk;
        float za[4] = {0, 0, 0, 0}, zb[4] = {0, 0, 0, 0};
        const float* h0 = &h1s[e * 64];
        const float* h1 = &h1s[e * 64 + 64];
        for (int j = 0; j < 64; ++j) {
            float4 wv = *(const float4*)&w2t[j * 132 + 4 * cg];
            float a = h0[j], bb = h1[j];
            za[0] += wv.x * a; za[1] += wv.y * a; za[2] += wv.z * a; za[3] += wv.w * a;
            zb[0] += wv.x * bb; zb[1] += wv.y * bb; zb[2] += wv.z * bb; zb[3] += wv.w * bb;
        }
#pragma unroll
        for (int c = 0; c < 4; ++c) {
            float ha = sc[c] * za[c] + sh[c]; ha = ha > 0.f ? ha : 0.f;
            float hb = sc[c] * zb[c] + sh[c]; hb = hb > 0.f ? hb : 0.f;
            mx[c] = fmaxf(mx[c], fmaxf(ha, hb));
        }
    }
#pragma unroll
    for (int c = 0; c < 4; ++c) mx[c] = fmaxf(mx[c], __shfl_xor(mx[c], 32));
    if (kh == 0) {
        float4 o; o.x = mx[0]; o.y = mx[1]; o.z = mx[2]; o.w = mx[3];
        *(float4*)&W[OFF_M + (b * NPTS + q0 + q) * 128 + 4 * cg] = o;
    }
}

// ------------- conv3 GEMM: z3 = m(32768x128) @ w3^T, 64x64 tiles -------------
template <bool STATS>
__global__ __launch_bounds__(256) void k_conv3(const float* __restrict__ w3, float* W) {
    __shared__ float mt[64 * 68];
    __shared__ float w3s[64 * 68];
    __shared__ float red[2 * 16 * 68];
    const int p0 = blockIdx.x * 64, c0 = blockIdx.y * 64;
    const int t = threadIdx.x, tr = t & 15, tc = t >> 4;
    float acc[4][4];
#pragma unroll
    for (int i = 0; i < 4; ++i)
#pragma unroll
        for (int c = 0; c < 4; ++c) acc[i][c] = 0.f;
    const float* M = &W[OFF_M];
    for (int kt = 0; kt < 2; ++kt) {
        if (kt) __syncthreads();
        for (int i = t; i < 8192; i += 256) {
            int p = i >> 6, j = i & 63;
            mt[p * 68 + j] = M[(p0 + p) * 128 + kt * 64 + j];
            w3s[p * 68 + j] = w3[(c0 + p) * 128 + kt * 64 + j];
        }
        __syncthreads();
        for (int jt = 0; jt < 16; ++jt) {
            float4 A[4], Bv[4];
#pragma unroll
            for (int i = 0; i < 4; ++i) A[i] = *(const float4*)&mt[(tr + 16 * i) * 68 + 4 * jt];
#pragma unroll
            for (int c = 0; c < 4; ++c) Bv[c] = *(const float4*)&w3s[(4 * tc + c) * 68 + 4 * jt];
#pragma unroll
            for (int i = 0; i < 4; ++i)
#pragma unroll
                for (int c = 0; c < 4; ++c)
                    acc[i][c] += A[i].x * Bv[c].x + A[i].y * Bv[c].y + A[i].z * Bv[c].z + A[i].w * Bv[c].w;
        }
    }
    __syncthreads();
    if (STATS) {
#pragma unroll
        for (int c = 0; c < 4; ++c) {
            float ps = 0, pq = 0;
#pragma unroll
            for (int i = 0; i < 4; ++i) { ps += acc[i][c]; pq += acc[i][c] * acc[i][c]; }
            red[tr * 68 + 4 * tc + c] = ps;
            red[1088 + tr * 68 + 4 * tc + c] = pq;
        }
        __syncthreads();
        if (t < 64) {
            float s = 0, q = 0;
            for (int r = 0; r < 16; ++r) { s += red[r * 68 + t]; q += red[1088 + r * 68 + t]; }
            atomicAdd(&W[OFF_SUM3 + c0 + t], s);
            atomicAdd(&W[OFF_SSQ3 + c0 + t], q);
        }
    } else {
        const int bb = p0 >> 12;
#pragma unroll
        for (int c = 0; c < 4; ++c) {
            int ch = c0 + 4 * tc + c;
            float sc = W[OFF_SC3 + ch], sh = W[OFF_SH3 + ch];
            float mx = 0.f;
#pragma unroll
            for (int i = 0; i < 4; ++i) {
                float h = sc * acc[i][c] + sh;
                mx = fmaxf(mx, h > 0.f ? h : 0.f);
            }
            red[tr * 68 + 4 * tc + c] = mx;
        }
        __syncthreads();
        if (t < 64) {
            float mx = 0.f;
            for (int r = 0; r < 16; ++r) mx = fmaxf(mx, red[r * 68 + t]);
            atomicMax((unsigned int*)&W[OFF_GMAX + bb * 1024 + c0 + t], __float_as_uint(mx));
        }
    }
}

__global__ void k_fin3(const float* __restrict__ g3, const float* __restrict__ b3, float* W) {
    int c = blockIdx.x * 256 + threadIdx.x;   // grid 4
    float mean = W[OFF_SUM3 + c] * (1.f / CNT3f);
    float var = W[OFF_SSQ3 + c] * (1.f / CNT3f) - mean * mean;
    float sc = g3[c] * rsqrtf(var + BNEPS);
    W[OFF_SC3 + c] = sc;
    W[OFF_SH3 + c] = b3[c] - mean * sc;
}

// ------------- z4 = gmax(8x1024) @ w4^T(512x1024) -------------
__global__ __launch_bounds__(256) void k_fc4(const float* __restrict__ w4, float* W) {
    __shared__ float red[256];
    const int t = threadIdx.x;
    const int oidx = t >> 3, s = t & 7;
    const int cc = oidx >> 3, b = oidx & 7;
    const int c = blockIdx.x * 4 + cc;
    const float* g = &W[OFF_GMAX];
    const float* wr = &w4[c * 1024 + s * 128];
    const float* gr = &g[b * 1024 + s * 128];
    float p = 0.f;
    for (int j = 0; j < 128; ++j) p += wr[j] * gr[j];
    red[t] = p;
    __syncthreads();
    if (t < 32) {
        float tot = 0.f;
        for (int k = 0; k < 8; ++k) tot += red[t * 8 + k];
        W[OFF_Z4 + (t & 7) * 512 + blockIdx.x * 4 + (t >> 3)] = tot;
    }
}

// ------------- tail: bn4+relu, fc5, bn5+relu, final linear + eye -------------
__global__ __launch_bounds__(512) void k_tail(const float* __restrict__ g4, const float* __restrict__ b4,
                                              const float* __restrict__ w5, const float* __restrict__ g5,
                                              const float* __restrict__ b5, const float* __restrict__ wl,
                                              const float* __restrict__ bl, float* W, float* __restrict__ out) {
    __shared__ float h4L[8 * 512];
    __shared__ float w5s[2 * 256 * 9];
    __shared__ float zp[2 * 2048];
    const int t = threadIdx.x;
    {   // bn4 + relu (stats over B=8)
        float v[8]; float s = 0.f, q = 0.f;
#pragma unroll
        for (int b = 0; b < 8; ++b) { v[b] = W[OFF_Z4 + b * 512 + t]; s += v[b]; q += v[b] * v[b]; }
        float mean = s * 0.125f;
        float var = q * 0.125f - mean * mean;
        float sc = g4[t] * rsqrtf(var + BNEPS);
        float sh = b4[t] - mean * sc;
#pragma unroll
        for (int b = 0; b < 8; ++b) {
            float h = sc * v[b] + sh;
            h4L[b * 512 + t] = h > 0.f ? h : 0.f;
        }
    }
    const int c5 = t & 255, half = t >> 8;
    float acc[8];
#pragma unroll
    for (int b = 0; b < 8; ++b) acc[b] = 0.f;
    for (int jt = 0; jt < 32; ++jt) {
        __syncthreads();
        for (int i = t; i < 4096; i += 512) {
            int h = i >> 11, rem = i & 2047;
            int ci = rem >> 3, jj = rem & 7;
            w5s[h * 2304 + ci * 9 + jj] = w5[ci * 512 + h * 256 + jt * 8 + jj];
        }
        __syncthreads();
#pragma unroll
        for (int jj = 0; jj < 8; ++jj) {
            float wv = w5s[half * 2304 + c5 * 9 + jj];
            int jg = half * 256 + jt * 8 + jj;
#pragma unroll
            for (int b = 0; b < 8; ++b) acc[b] += wv * h4L[b * 512 + jg];
        }
    }
#pragma unroll
    for (int b = 0; b < 8; ++b) zp[half * 2048 + b * 256 + c5] = acc[b];
    __syncthreads();
    if (t < 256) {   // combine halves, bn5 + relu
        float v[8], s = 0.f, q = 0.f;
#pragma unroll
        for (int b = 0; b < 8; ++b) {
            v[b] = zp[b * 256 + t] + zp[2048 + b * 256 + t];
            s += v[b]; q += v[b] * v[b];
        }
        float mean = s * 0.125f, var = q * 0.125f - mean * mean;
        float sc = g5[t] * rsqrtf(var + BNEPS), sh = b5[t] - mean * sc;
#pragma unroll
        for (int b = 0; b < 8; ++b) { float h = sc * v[b] + sh; zp[b * 256 + t] = h > 0.f ? h : 0.f; }
    }
    __syncthreads();
    if (t < 72) {
        int b = t / 9, r = t % 9;
        float a = bl[r] + ((r == 0 || r == 4 || r == 8) ? 1.f : 0.f);
        for (int j = 0; j < 256; ++j) a += wl[r * 256 + j] * zp[b * 256 + j];
        out[b * 9 + r] = a;
    }
}

extern "C" void kernel_launch(void* const* d_in, const int* in_sizes, int n_in,
                              void* d_out, int out_size, void* d_ws, size_t ws_size,
                              hipStream_t stream) {
    const float* x  = (const float*)d_in[0];
    const float* w1 = (const float*)d_in[1];
    const float* g1 = (const float*)d_in[2];
    const float* b1 = (const float*)d_in[3];
    const float* w2 = (const float*)d_in[4];
    const float* g2 = (const float*)d_in[5];
    const float* b2 = (const float*)d_in[6];
    const float* w3 = (const float*)d_in[7];
    const float* g3 = (const float*)d_in[8];
    const float* b3 = (const float*)d_in[9];
    const float* w4 = (const float*)d_in[10];
    const float* g4 = (const float*)d_in[11];
    const float* b4 = (const float*)d_in[12];
    const float* w5 = (const float*)d_in[13];
    const float* g5 = (const float*)d_in[14];
    const float* b5 = (const float*)d_in[15];
    const float* wl = (const float*)d_in[16];
    const float* bl = (const float*)d_in[17];
    float* W = (float*)d_ws;
    int* idx = (int*)d_ws;          // OFF_IDX == 0
    float* out = (float*)d_out;

    k_init<<<dim3(52), dim3(256), 0, stream>>>(W);
    k_knn<<<dim3(16, 8), dim3(256), 0, stream>>>(x, idx);
    k_c1stats<<<dim3(256, 8), dim3(256), 0, stream>>>(x, idx, w1, W);
    k_fin1<<<dim3(1), dim3(64), 0, stream>>>(g1, b1, W);
    k_c2stats<<<dim3(1024, 8), dim3(256), 0, stream>>>(x, idx, w1, w2, W);
    k_fin2<<<dim3(1), dim3(128), 0, stream>>>(g2, b2, W);
    k_c2apply<<<dim3(1024, 8), dim3(256), 0, stream>>>(x, idx, w1, w2, W);
    k_conv3<true><<<dim3(512, 16), dim3(256), 0, stream>>>(w3, W);
    k_fin3<<<dim3(4), dim3(256), 0, stream>>>(g3, b3, W);
    k_conv3<false><<<dim3(512, 16), dim3(256), 0, stream>>>(w3, W);
    k_fc4<<<dim3(128), dim3(256), 0, stream>>>(w4, W);
    k_tail<<<dim3(1), dim3(512), 0, stream>>>(g4, b4, w5, g5, b5, wl, bl, W, out);
}

// Round 2
// 1906.929 us; speedup vs baseline: 10.5264x; 10.5264x over previous
//
#include <hip/hip_runtime.h>

#define NPTS 4096
#define KNN 20
#define CNT1f 655360.0f   // B*N*K
#define CNT3f 32768.0f    // B*N
#define BNEPS 1e-5f

// ---- workspace layout (float offsets into d_ws) ----
// Phase aliasing: [idx region 0..655360) holds idx until k_c2apply is done,
// then is reused for G3/SM3/GMAX/Z4. [M region 655360..4849664) holds the
// phase-1 stats accumulators until fin2, then M overwrites them.
#define OFF_IDX   0
#define OFF_G3P   0          // 2*16384   (alias, after c2apply)
#define OFF_SM3P  32768      // 2*128
#define OFF_GMAX  33024      // 8*1024
#define OFF_Z4    41216      // 8*512
#define OFF_M     655360     // 32768*128
#define OFF_ES    655360     // 27 (pad 64)   (alias, before c2apply)
#define OFF_G1P   655424     // 4*4096
#define OFF_S1P   671808     // 4*64
#define ZERO1_BEG 655360
#define ZERO1_CNT 16704
#define ZERO2_BEG 0
#define ZERO2_CNT 41216
#define OFF_SC1   4849664
#define OFF_SH1   4849728
#define OFF_SC2   4849792
#define OFF_SH2   4849920
#define OFF_SC3   4850048
#define OFF_SH3   4851072
// end 4852096 floats = 18.5 MB (under round-0 proven footprint)

__global__ __launch_bounds__(256) void k_init(float* W, int beg, int cnt) {
    int i = blockIdx.x * 256 + threadIdx.x;
    if (i < cnt) W[beg + i] = 0.0f;
}

// -------- KNN (1 thread/query, points in LDS) + fused edge-stats (bn1) ------
__global__ __launch_bounds__(256) void k_knn(const float* __restrict__ x, int* __restrict__ idx, float* W) {
    __shared__ float px[NPTS], py[NPTS], pz[NPTS];   // 48 KB
    __shared__ float wred[4 * 27];
    const int b = blockIdx.y;
    const float* xb = x + b * 3 * NPTS;
    for (int i = threadIdx.x; i < NPTS; i += 256) {
        px[i] = xb[i]; py[i] = xb[NPTS + i]; pz[i] = xb[2 * NPTS + i];
    }
    __syncthreads();
    const int q = blockIdx.x * 256 + threadIdx.x;
    const float qx = px[q], qy = py[q], qz = pz[q];
    float bv[KNN]; int bi[KNN];
#pragma unroll
    for (int t = 0; t < KNN; ++t) { bv[t] = -3.0e38f; bi[t] = 0; }
    for (int j = 0; j < NPTS; ++j) {
        float dx = px[j] - qx, dy = py[j] - qy, dz = pz[j] - qz;
        float d = -(dx * dx + dy * dy + dz * dz);
        if (d > bv[KNN - 1]) {
            bv[KNN - 1] = d; bi[KNN - 1] = j;
#pragma unroll
            for (int p = KNN - 1; p > 0; --p) {
                if (bv[p] > bv[p - 1]) {
                    float tv = bv[p]; bv[p] = bv[p - 1]; bv[p - 1] = tv;
                    int ti = bi[p]; bi[p] = bi[p - 1]; bi[p - 1] = ti;
                }
            }
        }
    }
    const int base = (b * NPTS + q) * KNN;
#pragma unroll
    for (int t = 0; t < KNN; ++t) idx[base + t] = bi[t];
    // --- edge stats: Sum(e) [6] and upper-tri Sum(e e^T) [21] ---
    float st[27];
#pragma unroll
    for (int v = 0; v < 27; ++v) st[v] = 0.f;
    for (int t = 0; t < KNN; ++t) {
        int j = bi[t];
        float e[6];
        e[0] = qx; e[1] = qy; e[2] = qz;
        e[3] = px[j] - qx; e[4] = py[j] - qy; e[5] = pz[j] - qz;
        int id = 6;
#pragma unroll
        for (int i = 0; i < 6; ++i) {
            st[i] += e[i];
#pragma unroll
            for (int jj = 0; jj < 6; ++jj)
                if (jj >= i) { st[id] += e[i] * e[jj]; id++; }
        }
    }
#pragma unroll
    for (int v = 0; v < 27; ++v) {
        float s = st[v];
        s += __shfl_xor(s, 32); s += __shfl_xor(s, 16); s += __shfl_xor(s, 8);
        s += __shfl_xor(s, 4);  s += __shfl_xor(s, 2);  s += __shfl_xor(s, 1);
        st[v] = s;
    }
    const int lane = threadIdx.x & 63, wv = threadIdx.x >> 6;
    if (lane == 0)
#pragma unroll
        for (int v = 0; v < 27; ++v) wred[wv * 27 + v] = st[v];
    __syncthreads();
    if (threadIdx.x < 27)
        atomicAdd(&W[OFF_ES + threadIdx.x],
                  wred[threadIdx.x] + wred[27 + threadIdx.x] + wred[54 + threadIdx.x] + wred[81 + threadIdx.x]);
}

// bn1 affine from edge moments: var(w·e) = w E2 w^T /CNT - (w·S/CNT)^2
__global__ void k_fin1(const float* __restrict__ w1, const float* __restrict__ g1,
                       const float* __restrict__ b1, float* W) {
    __shared__ float es[27];
    const int c = threadIdx.x;
    if (c < 27) es[c] = W[OFF_ES + c];
    __syncthreads();
    float wr[6];
#pragma unroll
    for (int i = 0; i < 6; ++i) wr[i] = w1[c * 6 + i];
    float m = 0.f;
#pragma unroll
    for (int i = 0; i < 6; ++i) m += wr[i] * es[i];
    m *= (1.f / CNT1f);
    float qv = 0.f;
    int id = 6;
#pragma unroll
    for (int i = 0; i < 6; ++i)
#pragma unroll
        for (int jj = 0; jj < 6; ++jj)
            if (jj >= i) { qv += (jj == i ? 1.f : 2.f) * wr[i] * wr[jj] * es[id]; id++; }
    qv *= (1.f / CNT1f);
    float var = qv - m * m;
    float sc = g1[c] * rsqrtf(var + BNEPS);
    W[OFF_SC1 + c] = sc;
    W[OFF_SH1 + c] = b1[c] - m * sc;
}

// -------- pass A: accumulate Sum(h1) and G1 = Sum(h1 h1^T) over all edges ----
__global__ __launch_bounds__(256) void k_gram1(const float* __restrict__ x, const int* __restrict__ idx,
                                               const float* __restrict__ w1, float* W) {
    __shared__ float eds[160 * 6];     // 960
    __shared__ float h1s[160 * 68];    // 10880  (chan-inner, padded 68)
    const int t = threadIdx.x;
    const int b = blockIdx.x >> 5, q0 = (blockIdx.x & 31) * 128;
    const float* xb = x + b * 3 * NPTS;
    const int j64 = t & 63, grp = t >> 6;
    float wr[6];
#pragma unroll
    for (int i = 0; i < 6; ++i) wr[i] = w1[j64 * 6 + i];
    const float sc = W[OFF_SC1 + j64], sh = W[OFF_SH1 + j64];
    const int rr = t & 15, cc = t >> 4;
    float acc[4][4];
#pragma unroll
    for (int i = 0; i < 4; ++i)
#pragma unroll
        for (int j = 0; j < 4; ++j) acc[i][j] = 0.f;
    float ssum = 0.f;
    const int ebase = (b * NPTS + q0) * KNN;
    for (int ch = 0; ch < 16; ++ch) {
        __syncthreads();
        if (t < 160) {
            int eg = ch * 160 + t;
            int q = q0 + eg / KNN;
            int jn = idx[ebase + eg];
            float cx = xb[q], cy = xb[NPTS + q], cz = xb[2 * NPTS + q];
            float* E = &eds[t * 6];
            E[0] = cx; E[1] = cy; E[2] = cz;
            E[3] = xb[jn] - cx; E[4] = xb[NPTS + jn] - cy; E[5] = xb[2 * NPTS + jn] - cz;
        }
        __syncthreads();
        for (int e = grp * 40; e < grp * 40 + 40; ++e) {
            const float* E = &eds[e * 6];
            float z = wr[0] * E[0] + wr[1] * E[1] + wr[2] * E[2] + wr[3] * E[3] + wr[4] * E[4] + wr[5] * E[5];
            float h = sc * z + sh;
            h1s[e * 68 + j64] = h > 0.f ? h : 0.f;
        }
        __syncthreads();
#pragma unroll 2
        for (int e = 0; e < 160; ++e) {
            float4 fa = *(const float4*)&h1s[e * 68 + 4 * rr];
            float4 fb = *(const float4*)&h1s[e * 68 + 4 * cc];
            acc[0][0] += fa.x * fb.x; acc[0][1] += fa.x * fb.y; acc[0][2] += fa.x * fb.z; acc[0][3] += fa.x * fb.w;
            acc[1][0] += fa.y * fb.x; acc[1][1] += fa.y * fb.y; acc[1][2] += fa.y * fb.z; acc[1][3] += fa.y * fb.w;
            acc[2][0] += fa.z * fb.x; acc[2][1] += fa.z * fb.y; acc[2][2] += fa.z * fb.z; acc[2][3] += fa.z * fb.w;
            acc[3][0] += fa.w * fb.x; acc[3][1] += fa.w * fb.y; acc[3][2] += fa.w * fb.z; acc[3][3] += fa.w * fb.w;
        }
        for (int e = grp; e < 160; e += 4) ssum += h1s[e * 68 + j64];
    }
    const int part = blockIdx.x & 3;
    float* Gp = &W[OFF_G1P + part * 4096];
#pragma unroll
    for (int i = 0; i < 4; ++i)
#pragma unroll
        for (int j = 0; j < 4; ++j)
            atomicAdd(&Gp[(4 * rr + i) * 64 + 4 * cc + j], acc[i][j]);
    atomicAdd(&W[OFF_S1P + part * 64 + j64], ssum);
}

// bn2 affine from Gram: var(w2_c·h1) = w2_c G w2_c^T/CNT - mean^2
__global__ __launch_bounds__(256) void k_fin2(const float* __restrict__ w2, const float* __restrict__ g2,
                                              const float* __restrict__ b2, float* W) {
    __shared__ float Gs[4096];
    __shared__ float s1s[64];
    __shared__ float w2s[128 * 65];
    const int t = threadIdx.x;
    for (int i = t; i < 4096; i += 256)
        Gs[i] = W[OFF_G1P + i] + W[OFF_G1P + 4096 + i] + W[OFF_G1P + 8192 + i] + W[OFF_G1P + 12288 + i];
    if (t < 64) s1s[t] = W[OFF_S1P + t] + W[OFF_S1P + 64 + t] + W[OFF_S1P + 128 + t] + W[OFF_S1P + 192 + t];
    for (int i = t; i < 8192; i += 256) w2s[(i >> 6) * 65 + (i & 63)] = w2[i];
    __syncthreads();
    const int c = t >> 1, half = t & 1;
    float acc = 0.f;
    for (int ii = 0; ii < 32; ++ii) {
        int i = 32 * half + ii;
        float wi = w2s[c * 65 + i];
        float inner = 0.f;
        for (int j = 0; j < 64; ++j) inner += Gs[i * 64 + j] * w2s[c * 65 + j];
        acc += wi * inner;
    }
    acc += __shfl_xor(acc, 1);
    if (half == 0) {
        float ms = 0.f;
        for (int j = 0; j < 64; ++j) ms += w2s[c * 65 + j] * s1s[j];
        float mean = ms * (1.f / CNT1f);
        float var = acc * (1.f / CNT1f) - mean * mean;
        float sc = g2[c] * rsqrtf(var + BNEPS);
        W[OFF_SC2 + c] = sc;
        W[OFF_SH2 + c] = b2[c] - mean * sc;
    }
}

// -------- pass B: conv1+bn1+relu -> conv2+bn2+relu -> max over K -> M --------
__global__ __launch_bounds__(320) void k_c2apply(const float* __restrict__ x, const int* __restrict__ idx,
                                                 const float* __restrict__ w1, const float* __restrict__ w2,
                                                 float* W) {
    __shared__ float w2t[64 * 132];       // [j][chan], padded
    __shared__ float h1t[64 * 84];        // [j][edge], padded
    __shared__ float eds[80 * 6];
    __shared__ unsigned int maxb[4 * 128];
    const int t = threadIdx.x;
    const int b = blockIdx.y, q0 = blockIdx.x * 4;
    const float* xb = x + b * 3 * NPTS;
    const int ebase = (b * NPTS + q0) * KNN;
    for (int i = t; i < 8192; i += 320) w2t[(i & 63) * 132 + (i >> 6)] = w2[i];
    if (t < 80) {
        int q = q0 + t / KNN;
        int jn = idx[ebase + t];
        float cx = xb[q], cy = xb[NPTS + q], cz = xb[2 * NPTS + q];
        float* E = &eds[t * 6];
        E[0] = cx; E[1] = cy; E[2] = cz;
        E[3] = xb[jn] - cx; E[4] = xb[NPTS + jn] - cy; E[5] = xb[2 * NPTS + jn] - cz;
    }
    for (int i = t; i < 512; i += 320) maxb[i] = 0u;
    __syncthreads();
    {
        const int j64 = t & 63, grp = t >> 6;   // grp 0..4
        float wr[6];
#pragma unroll
        for (int i = 0; i < 6; ++i) wr[i] = w1[j64 * 6 + i];
        const float sc = W[OFF_SC1 + j64], sh = W[OFF_SH1 + j64];
        for (int e = grp * 16; e < grp * 16 + 16; ++e) {
            const float* E = &eds[e * 6];
            float z = wr[0] * E[0] + wr[1] * E[1] + wr[2] * E[2] + wr[3] * E[3] + wr[4] * E[4] + wr[5] * E[5];
            float h = sc * z + sh;
            h1t[j64 * 84 + e] = h > 0.f ? h : 0.f;
        }
    }
    __syncthreads();
    const int cg = t & 31, slot = t >> 5;   // 32 chan-groups x 10 slots
    float sc2[4], sh2[4];
#pragma unroll
    for (int c = 0; c < 4; ++c) { sc2[c] = W[OFF_SC2 + 4 * cg + c]; sh2[c] = W[OFF_SH2 + 4 * cg + c]; }
    for (int it = 0; it < 2; ++it) {
        int g = it * 10 + slot;            // 0..19
        int q = g / 5, kp = g - 5 * q;
        int e0 = q * 20 + 4 * kp;
        float a0x = 0.f, a0y = 0.f, a0z = 0.f, a0w = 0.f;
        float a1x = 0.f, a1y = 0.f, a1z = 0.f, a1w = 0.f;
        float a2x = 0.f, a2y = 0.f, a2z = 0.f, a2w = 0.f;
        float a3x = 0.f, a3y = 0.f, a3z = 0.f, a3w = 0.f;
#pragma unroll 4
        for (int j = 0; j < 64; ++j) {
            float4 wvv = *(const float4*)&w2t[j * 132 + 4 * cg];
            float4 hv = *(const float4*)&h1t[j * 84 + e0];
            a0x += hv.x * wvv.x; a0y += hv.x * wvv.y; a0z += hv.x * wvv.z; a0w += hv.x * wvv.w;
            a1x += hv.y * wvv.x; a1y += hv.y * wvv.y; a1z += hv.y * wvv.z; a1w += hv.y * wvv.w;
            a2x += hv.z * wvv.x; a2y += hv.z * wvv.y; a2z += hv.z * wvv.z; a2w += hv.z * wvv.w;
            a3x += hv.w * wvv.x; a3y += hv.w * wvv.y; a3z += hv.w * wvv.z; a3w += hv.w * wvv.w;
        }
        float em[4];
        em[0] = fmaxf(fmaxf(sc2[0] * a0x + sh2[0], sc2[0] * a1x + sh2[0]),
                      fmaxf(sc2[0] * a2x + sh2[0], sc2[0] * a3x + sh2[0]));
        em[1] = fmaxf(fmaxf(sc2[1] * a0y + sh2[1], sc2[1] * a1y + sh2[1]),
                      fmaxf(sc2[1] * a2y + sh2[1], sc2[1] * a3y + sh2[1]));
        em[2] = fmaxf(fmaxf(sc2[2] * a0z + sh2[2], sc2[2] * a1z + sh2[2]),
                      fmaxf(sc2[2] * a2z + sh2[2], sc2[2] * a3z + sh2[2]));
        em[3] = fmaxf(fmaxf(sc2[3] * a0w + sh2[3], sc2[3] * a1w + sh2[3]),
                      fmaxf(sc2[3] * a2w + sh2[3], sc2[3] * a3w + sh2[3]));
#pragma unroll
        for (int c = 0; c < 4; ++c) {
            float v = em[c] > 0.f ? em[c] : 0.f;
            atomicMax(&maxb[q * 128 + 4 * cg + c], __float_as_uint(v));
        }
    }
    __syncthreads();
    if (t < 128) {
        int q = t >> 5, c4 = t & 31;
        float4 o;
        o.x = __uint_as_float(maxb[q * 128 + 4 * c4 + 0]);
        o.y = __uint_as_float(maxb[q * 128 + 4 * c4 + 1]);
        o.z = __uint_as_float(maxb[q * 128 + 4 * c4 + 2]);
        o.w = __uint_as_float(maxb[q * 128 + 4 * c4 + 3]);
        *(float4*)&W[OFF_M + (b * NPTS + q0 + q) * 128 + 4 * c4] = o;
    }
}

// -------- G3 = M^T M (128x128) and Sum(m) for bn3 ---------------------------
__global__ __launch_bounds__(256) void k_gram3(float* W) {
    __shared__ float Ms[64 * 132];
    const int t = threadIdx.x;
    const int rg = t & 15, cg = t >> 4;
    const int r0 = blockIdx.x * 512;
    const float* M = &W[OFF_M];
    float acc[8][8];
#pragma unroll
    for (int i = 0; i < 8; ++i)
#pragma unroll
        for (int j = 0; j < 8; ++j) acc[i][j] = 0.f;
    float smacc = 0.f;
    for (int ch = 0; ch < 8; ++ch) {
        __syncthreads();
        for (int i = t; i < 8192; i += 256)
            Ms[(i >> 7) * 132 + (i & 127)] = M[(r0 + ch * 64) * 128 + i];
        __syncthreads();
#pragma unroll 2
        for (int e = 0; e < 64; ++e) {
            float4 x0 = *(const float4*)&Ms[e * 132 + 8 * rg];
            float4 x1 = *(const float4*)&Ms[e * 132 + 8 * rg + 4];
            float4 y0 = *(const float4*)&Ms[e * 132 + 8 * cg];
            float4 y1 = *(const float4*)&Ms[e * 132 + 8 * cg + 4];
            float av[8] = {x0.x, x0.y, x0.z, x0.w, x1.x, x1.y, x1.z, x1.w};
            float bv[8] = {y0.x, y0.y, y0.z, y0.w, y1.x, y1.y, y1.z, y1.w};
#pragma unroll
            for (int i = 0; i < 8; ++i)
#pragma unroll
                for (int j = 0; j < 8; ++j) acc[i][j] += av[i] * bv[j];
        }
        if (t < 128) {
            float s = 0.f;
            for (int e = 0; e < 64; ++e) s += Ms[e * 132 + t];
            smacc += s;
        }
    }
    const int part = blockIdx.x & 1;
    float* Gp = &W[OFF_G3P + part * 16384];
#pragma unroll
    for (int i = 0; i < 8; ++i)
#pragma unroll
        for (int j = 0; j < 8; ++j)
            atomicAdd(&Gp[(8 * rg + i) * 128 + 8 * cg + j], acc[i][j]);
    if (t < 128) atomicAdd(&W[OFF_SM3P + part * 128 + t], smacc);
}

// bn3 affine: 16 channels per block
__global__ __launch_bounds__(256) void k_fin3(const float* __restrict__ w3, const float* __restrict__ g3,
                                              const float* __restrict__ b3, float* W) {
    __shared__ float G3s[128 * 129];
    __shared__ float w3s[16 * 132];
    __shared__ float sm3[128];
    __shared__ float red[256];
    __shared__ float mred[16];
    const int t = threadIdx.x;
    const int c0 = blockIdx.x * 16;
    for (int i = t; i < 16384; i += 256)
        G3s[(i >> 7) * 129 + (i & 127)] = W[OFF_G3P + i] + W[OFF_G3P + 16384 + i];
    for (int i = t; i < 2048; i += 256)
        w3s[(i >> 7) * 132 + (i & 127)] = w3[(c0 + (i >> 7)) * 128 + (i & 127)];
    if (t < 128) sm3[t] = W[OFF_SM3P + t] + W[OFF_SM3P + 128 + t];
    __syncthreads();
    const int cl = t >> 4, seg = t & 15;
    float acc = 0.f;
    for (int ii = 0; ii < 8; ++ii) {
        int i = 8 * seg + ii;
        float wi = w3s[cl * 132 + i];
        float inner = 0.f;
        for (int j = 0; j < 128; ++j) inner += G3s[i * 129 + j] * w3s[cl * 132 + j];
        acc += wi * inner;
    }
    red[t] = acc;
    if (seg == 0) {
        float ms = 0.f;
        for (int j = 0; j < 128; ++j) ms += w3s[cl * 132 + j] * sm3[j];
        mred[cl] = ms;
    }
    __syncthreads();
    if (t < 16) {
        float s = 0.f;
#pragma unroll
        for (int k = 0; k < 16; ++k) s += red[t * 16 + k];
        float mean = mred[t] * (1.f / CNT3f);
        float var = s * (1.f / CNT3f) - mean * mean;
        float sc = g3[c0 + t] * rsqrtf(var + BNEPS);
        W[OFF_SC3 + c0 + t] = sc;
        W[OFF_SH3 + c0 + t] = b3[c0 + t] - mean * sc;
    }
}

// -------- conv3 apply: z3 = M @ w3^T, bn3+relu, max over N -> GMAX ----------
__global__ __launch_bounds__(256) void k_conv3(const float* __restrict__ w3, float* W) {
    __shared__ float mt[64 * 68];
    __shared__ float w3s[64 * 68];
    __shared__ float red[16 * 68];
    const int p0 = blockIdx.x * 64, c0 = blockIdx.y * 64;
    const int t = threadIdx.x, tr = t & 15, tc = t >> 4;
    float acc[4][4];
#pragma unroll
    for (int i = 0; i < 4; ++i)
#pragma unroll
        for (int c = 0; c < 4; ++c) acc[i][c] = 0.f;
    const float* M = &W[OFF_M];
    for (int kt = 0; kt < 2; ++kt) {
        if (kt) __syncthreads();
        for (int i = t; i < 8192; i += 256) {
            int p = i >> 6, j = i & 63;
            mt[p * 68 + j] = M[(p0 + p) * 128 + kt * 64 + j];
            w3s[p * 68 + j] = w3[(c0 + p) * 128 + kt * 64 + j];
        }
        __syncthreads();
        for (int jt = 0; jt < 16; ++jt) {
            float4 A[4], Bv[4];
#pragma unroll
            for (int i = 0; i < 4; ++i) A[i] = *(const float4*)&mt[(tr + 16 * i) * 68 + 4 * jt];
#pragma unroll
            for (int c = 0; c < 4; ++c) Bv[c] = *(const float4*)&w3s[(4 * tc + c) * 68 + 4 * jt];
#pragma unroll
            for (int i = 0; i < 4; ++i)
#pragma unroll
                for (int c = 0; c < 4; ++c)
                    acc[i][c] += A[i].x * Bv[c].x + A[i].y * Bv[c].y + A[i].z * Bv[c].z + A[i].w * Bv[c].w;
        }
    }
    __syncthreads();
    const int bb = p0 >> 12;
#pragma unroll
    for (int c = 0; c < 4; ++c) {
        int chn = c0 + 4 * tc + c;
        float sc = W[OFF_SC3 + chn], sh = W[OFF_SH3 + chn];
        float mx = 0.f;
#pragma unroll
        for (int i = 0; i < 4; ++i) {
            float h = sc * acc[i][c] + sh;
            mx = fmaxf(mx, h > 0.f ? h : 0.f);
        }
        red[tr * 68 + 4 * tc + c] = mx;
    }
    __syncthreads();
    if (t < 64) {
        float mx = 0.f;
        for (int r = 0; r < 16; ++r) mx = fmaxf(mx, red[r * 68 + t]);
        atomicMax((unsigned int*)&W[OFF_GMAX + bb * 1024 + c0 + t], __float_as_uint(mx));
    }
}

// -------- z4 = gmax(8x1024) @ w4^T(512x1024) --------------------------------
__global__ __launch_bounds__(256) void k_fc4(const float* __restrict__ w4, float* W) {
    __shared__ float red[256];
    const int t = threadIdx.x;
    const int oidx = t >> 3, s = t & 7;
    const int cc = oidx >> 3, b = oidx & 7;
    const int c = blockIdx.x * 4 + cc;
    const float* g = &W[OFF_GMAX];
    const float* wr = &w4[c * 1024 + s * 128];
    const float* gr = &g[b * 1024 + s * 128];
    float p = 0.f;
    for (int j = 0; j < 128; ++j) p += wr[j] * gr[j];
    red[t] = p;
    __syncthreads();
    if (t < 32) {
        float tot = 0.f;
        for (int k = 0; k < 8; ++k) tot += red[t * 8 + k];
        W[OFF_Z4 + (t & 7) * 512 + blockIdx.x * 4 + (t >> 3)] = tot;
    }
}

// -------- tail: bn4+relu, fc5, bn5+relu, final linear + eye -----------------
__global__ __launch_bounds__(512) void k_tail(const float* __restrict__ g4, const float* __restrict__ b4,
                                              const float* __restrict__ w5, const float* __restrict__ g5,
                                              const float* __restrict__ b5, const float* __restrict__ wl,
                                              const float* __restrict__ bl, float* W, float* __restrict__ out) {
    __shared__ float h4L[8 * 512];
    __shared__ float w5s[2 * 256 * 9];
    __shared__ float zp[2 * 2048];
    const int t = threadIdx.x;
    {
        float v[8]; float s = 0.f, q = 0.f;
#pragma unroll
        for (int b = 0; b < 8; ++b) { v[b] = W[OFF_Z4 + b * 512 + t]; s += v[b]; q += v[b] * v[b]; }
        float mean = s * 0.125f;
        float var = q * 0.125f - mean * mean;
        float sc = g4[t] * rsqrtf(var + BNEPS);
        float sh = b4[t] - mean * sc;
#pragma unroll
        for (int b = 0; b < 8; ++b) {
            float h = sc * v[b] + sh;
            h4L[b * 512 + t] = h > 0.f ? h : 0.f;
        }
    }
    const int c5 = t & 255, half = t >> 8;
    float acc[8];
#pragma unroll
    for (int b = 0; b < 8; ++b) acc[b] = 0.f;
    for (int jt = 0; jt < 32; ++jt) {
        __syncthreads();
        for (int i = t; i < 4096; i += 512) {
            int h = i >> 11, rem = i & 2047;
            int ci = rem >> 3, jj = rem & 7;
            w5s[h * 2304 + ci * 9 + jj] = w5[ci * 512 + h * 256 + jt * 8 + jj];
        }
        __syncthreads();
#pragma unroll
        for (int jj = 0; jj < 8; ++jj) {
            float wv = w5s[half * 2304 + c5 * 9 + jj];
            int jg = half * 256 + jt * 8 + jj;
#pragma unroll
            for (int b = 0; b < 8; ++b) acc[b] += wv * h4L[b * 512 + jg];
        }
    }
#pragma unroll
    for (int b = 0; b < 8; ++b) zp[half * 2048 + b * 256 + c5] = acc[b];
    __syncthreads();
    if (t < 256) {
        float v[8], s = 0.f, q = 0.f;
#pragma unroll
        for (int b = 0; b < 8; ++b) {
            v[b] = zp[b * 256 + t] + zp[2048 + b * 256 + t];
            s += v[b]; q += v[b] * v[b];
        }
        float mean = s * 0.125f, var = q * 0.125f - mean * mean;
        float sc = g5[t] * rsqrtf(var + BNEPS), sh = b5[t] - mean * sc;
#pragma unroll
        for (int b = 0; b < 8; ++b) { float h = sc * v[b] + sh; zp[b * 256 + t] = h > 0.f ? h : 0.f; }
    }
    __syncthreads();
    if (t < 72) {
        int b = t / 9, r = t % 9;
        float a = bl[r] + ((r == 0 || r == 4 || r == 8) ? 1.f : 0.f);
        for (int j = 0; j < 256; ++j) a += wl[r * 256 + j] * zp[b * 256 + j];
        out[b * 9 + r] = a;
    }
}

extern "C" void kernel_launch(void* const* d_in, const int* in_sizes, int n_in,
                              void* d_out, int out_size, void* d_ws, size_t ws_size,
                              hipStream_t stream) {
    const float* x  = (const float*)d_in[0];
    const float* w1 = (const float*)d_in[1];
    const float* g1 = (const float*)d_in[2];
    const float* b1 = (const float*)d_in[3];
    const float* w2 = (const float*)d_in[4];
    const float* g2 = (const float*)d_in[5];
    const float* b2 = (const float*)d_in[6];
    const float* w3 = (const float*)d_in[7];
    const float* g3 = (const float*)d_in[8];
    const float* b3 = (const float*)d_in[9];
    const float* w4 = (const float*)d_in[10];
    const float* g4 = (const float*)d_in[11];
    const float* b4 = (const float*)d_in[12];
    const float* w5 = (const float*)d_in[13];
    const float* g5 = (const float*)d_in[14];
    const float* b5 = (const float*)d_in[15];
    const float* wl = (const float*)d_in[16];
    const float* bl = (const float*)d_in[17];
    float* W = (float*)d_ws;
    int* idx = (int*)d_ws;
    float* out = (float*)d_out;

    k_init<<<dim3(66), dim3(256), 0, stream>>>(W, ZERO1_BEG, ZERO1_CNT);
    k_knn<<<dim3(16, 8), dim3(256), 0, stream>>>(x, idx, W);
    k_fin1<<<dim3(1), dim3(64), 0, stream>>>(w1, g1, b1, W);
    k_gram1<<<dim3(256), dim3(256), 0, stream>>>(x, idx, w1, W);
    k_fin2<<<dim3(1), dim3(256), 0, stream>>>(w2, g2, b2, W);
    k_c2apply<<<dim3(1024, 8), dim3(320), 0, stream>>>(x, idx, w1, w2, W);
    k_init<<<dim3(161), dim3(256), 0, stream>>>(W, ZERO2_BEG, ZERO2_CNT);
    k_gram3<<<dim3(64), dim3(256), 0, stream>>>(W);
    k_fin3<<<dim3(64), dim3(256), 0, stream>>>(w3, g3, b3, W);
    k_conv3<<<dim3(512, 16), dim3(256), 0, stream>>>(w3, W);
    k_fc4<<<dim3(128), dim3(256), 0, stream>>>(w4, W);
    k_tail<<<dim3(1), dim3(512), 0, stream>>>(g4, b4, w5, g5, b5, wl, bl, W, out);
}

// Round 3
// 1332.592 us; speedup vs baseline: 15.0632x; 1.4310x over previous
//
#include <hip/hip_runtime.h>

#define NPTS 4096
#define KNN 20
#define CNT1f 655360.0f   // B*N*K
#define CNT3f 32768.0f    // B*N
#define BNEPS 1e-5f

// ---- workspace layout (float offsets into d_ws) ----
// Phase aliasing: [idx region 0..655360) holds idx until k_c2apply is done,
// then is reused for G3/SM3/GMAX/Z4. [M region 655360..4849664) holds the
// phase-1 stats accumulators until fin2, then M overwrites them.
#define OFF_IDX   0
#define OFF_G3P   0          // 2*16384   (alias, after c2apply)
#define OFF_SM3P  32768      // 2*128
#define OFF_GMAX  33024      // 8*1024
#define OFF_Z4    41216      // 8*512
#define OFF_M     655360     // 32768*128
#define OFF_ES    655360     // 32 partials x 32 (27 used)  (alias, pre-c2apply)
#define OFF_G1P   656384     // 4*4096
#define OFF_S1P   672768     // 4*64
#define ZERO1_BEG 655360
#define ZERO1_CNT 17664
#define ZERO2_BEG 0
#define ZERO2_CNT 41216
#define OFF_SC1   4849664
#define OFF_SH1   4849728
#define OFF_SC2   4849792
#define OFF_SH2   4849920
#define OFF_SC3   4850048
#define OFF_SH3   4851072

__global__ __launch_bounds__(256) void k_init(float* W, int beg, int cnt) {
    int i = blockIdx.x * 256 + threadIdx.x;
    if (i < cnt) W[beg + i] = 0.0f;
}

// ---- wave-wide: find bin B containing the K-th smallest (1-indexed) in H ----
template <int PER>
__device__ __forceinline__ void wave_scan_find(const int* H, int K, int lane,
                                               int& B, int& below, int& hB) {
    int c[PER]; int s = 0;
    const int base = lane * PER;
#pragma unroll
    for (int p = 0; p < PER; ++p) { c[p] = H[base + p]; s += c[p]; }
    int pre = s;
#pragma unroll
    for (int off = 1; off < 64; off <<= 1) {
        int t = __shfl_up(pre, off, 64);
        if (lane >= off) pre += t;
    }
    int excl = pre - s;
    bool has = (excl < K) && (K <= excl + s);
    unsigned long long m = __ballot(has);
    int src = (int)(__ffsll((unsigned long long)m) - 1);
    int mb = 0, mbelow = 0, mh = 0;
    if (lane == src) {
        int cum = excl;
#pragma unroll
        for (int p = 0; p < PER; ++p) {
            if (cum < K && K <= cum + c[p]) { mb = base + p; mbelow = cum; mh = c[p]; break; }
            cum += c[p];
        }
    }
    B = __shfl(mb, src, 64);
    below = __shfl(mbelow, src, 64);
    hB = __shfl(mh, src, 64);
}

// -------- KNN via radix-select: 1 wave/query, 4 queries/block ---------------
// Downstream consumers (max over K, sums over K) are order-invariant, so we
// only need the top-20 SET. Histogram exponent bins, refine 9 bits/level to
// a 27-bit threshold (early exit when boundary bin count == remainder).
__global__ __launch_bounds__(256) void k_knn(const float* __restrict__ x, int* __restrict__ idx, float* W) {
    __shared__ float px[NPTS], py[NPTS], pz[NPTS];   // 48 KB
    __shared__ int hist[4][512];
    __shared__ int outi[4][20];
    __shared__ int cnts[4][2];
    __shared__ float estat[27];
    const int tid = threadIdx.x;
    const int b = blockIdx.y;
    const float* xb = x + b * 3 * NPTS;
    for (int i = tid; i < NPTS; i += 256) {
        px[i] = xb[i]; py[i] = xb[NPTS + i]; pz[i] = xb[2 * NPTS + i];
    }
    if (tid < 27) estat[tid] = 0.f;
    if (tid < 8) cnts[tid >> 1][tid & 1] = 0;
    __syncthreads();
    const int wv = tid >> 6, lane = tid & 63;
    const int q = blockIdx.x * 4 + wv;
    const float qx = px[q], qy = py[q], qz = pz[q];
    int* H = hist[wv];

    // level 0: 256 bins = d2 bits >> 23 (d2 >= 0 so uint order == float order)
#pragma unroll
    for (int p = 0; p < 4; ++p) H[lane * 4 + p] = 0;
    for (int it = 0; it < 64; ++it) {
        int j = it * 64 + lane;
        float dx = px[j] - qx, dy = py[j] - qy, dz = pz[j] - qz;
        float d = fmaf(dx, dx, fmaf(dy, dy, dz * dz));
        atomicAdd(&H[__float_as_uint(d) >> 23], 1);
    }
    int B, below, hB;
    wave_scan_find<4>(H, KNN, lane, B, below, hB);
    unsigned int P = (unsigned int)B;
    int rem = KNN - below;
    int S = 23;
    if (hB != rem) {
        // level 1: 512 bins of bits[22:14] among prefix-matching candidates
#pragma unroll
        for (int p = 0; p < 8; ++p) H[lane * 8 + p] = 0;
        for (int it = 0; it < 64; ++it) {
            int j = it * 64 + lane;
            float dx = px[j] - qx, dy = py[j] - qy, dz = pz[j] - qz;
            float d = fmaf(dx, dx, fmaf(dy, dy, dz * dz));
            unsigned int u = __float_as_uint(d);
            if ((u >> 23) == P) atomicAdd(&H[(u >> 14) & 511], 1);
        }
        wave_scan_find<8>(H, rem, lane, B, below, hB);
        P = (P << 9) | (unsigned int)B;
        rem -= below;
        S = 14;
        if (hB != rem) {
            // level 2: bits[13:5] -> 27-bit threshold (ties beyond are measure-zero)
#pragma unroll
            for (int p = 0; p < 8; ++p) H[lane * 8 + p] = 0;
            for (int it = 0; it < 64; ++it) {
                int j = it * 64 + lane;
                float dx = px[j] - qx, dy = py[j] - qy, dz = pz[j] - qz;
                float d = fmaf(dx, dx, fmaf(dy, dy, dz * dz));
                unsigned int u = __float_as_uint(d);
                if ((u >> 14) == P) atomicAdd(&H[(u >> 5) & 511], 1);
            }
            wave_scan_find<8>(H, rem, lane, B, below, hB);
            P = (P << 9) | (unsigned int)B;
            rem -= below;
            S = 5;
        }
    }
    // compact: all keys < P, plus first `rem` keys == P
    int* OC = cnts[wv];
    for (int it = 0; it < 64; ++it) {
        int j = it * 64 + lane;
        float dx = px[j] - qx, dy = py[j] - qy, dz = pz[j] - qz;
        float d = fmaf(dx, dx, fmaf(dy, dy, dz * dz));
        unsigned int key = __float_as_uint(d) >> S;
        if (key <= P) {
            bool take = true;
            if (key == P) { int e = atomicAdd(&OC[1], 1); take = (e < rem); }
            if (take) { int pos = atomicAdd(&OC[0], 1); outi[wv][pos] = j; }
        }
    }
    const int obase = (b * NPTS + q) * KNN;
    if (lane < KNN) idx[obase + lane] = outi[wv][lane];
    // fused edge moments for bn1: Sum(e) [6] + upper-tri Sum(e e^T) [21]
    float st[27];
#pragma unroll
    for (int v = 0; v < 27; ++v) st[v] = 0.f;
    if (lane < KNN) {
        int j = outi[wv][lane];
        float e[6];
        e[0] = qx; e[1] = qy; e[2] = qz;
        e[3] = px[j] - qx; e[4] = py[j] - qy; e[5] = pz[j] - qz;
        int id = 6;
#pragma unroll
        for (int i = 0; i < 6; ++i) {
            st[i] = e[i];
#pragma unroll
            for (int jj = i; jj < 6; ++jj) { st[id] = e[i] * e[jj]; id++; }
        }
    }
#pragma unroll
    for (int v = 0; v < 27; ++v) {
        float s = st[v];
        s += __shfl_xor(s, 32); s += __shfl_xor(s, 16); s += __shfl_xor(s, 8);
        s += __shfl_xor(s, 4);  s += __shfl_xor(s, 2);  s += __shfl_xor(s, 1);
        st[v] = s;
    }
    if (lane == 0) {
#pragma unroll
        for (int v = 0; v < 27; ++v) atomicAdd(&estat[v], st[v]);
    }
    __syncthreads();
    if (tid < 27) atomicAdd(&W[OFF_ES + (blockIdx.x & 31) * 32 + tid], estat[tid]);
}

// bn1 affine from edge moments: var(w·e) = w E2 w^T /CNT - (w·S/CNT)^2
__global__ void k_fin1(const float* __restrict__ w1, const float* __restrict__ g1,
                       const float* __restrict__ b1, float* W) {
    __shared__ float es[27];
    const int c = threadIdx.x;
    if (c < 27) {
        float s = 0.f;
        for (int p = 0; p < 32; ++p) s += W[OFF_ES + p * 32 + c];
        es[c] = s;
    }
    __syncthreads();
    float wr[6];
#pragma unroll
    for (int i = 0; i < 6; ++i) wr[i] = w1[c * 6 + i];
    float m = 0.f;
#pragma unroll
    for (int i = 0; i < 6; ++i) m += wr[i] * es[i];
    m *= (1.f / CNT1f);
    float qv = 0.f;
    int id = 6;
#pragma unroll
    for (int i = 0; i < 6; ++i)
#pragma unroll
        for (int jj = 0; jj < 6; ++jj)
            if (jj >= i) { qv += (jj == i ? 1.f : 2.f) * wr[i] * wr[jj] * es[id]; id++; }
    qv *= (1.f / CNT1f);
    float var = qv - m * m;
    float sc = g1[c] * rsqrtf(var + BNEPS);
    W[OFF_SC1 + c] = sc;
    W[OFF_SH1 + c] = b1[c] - m * sc;
}

// -------- pass A: accumulate Sum(h1) and G1 = Sum(h1 h1^T) over all edges ----
__global__ __launch_bounds__(256) void k_gram1(const float* __restrict__ x, const int* __restrict__ idx,
                                               const float* __restrict__ w1, float* W) {
    __shared__ float eds[160 * 6];     // 960
    __shared__ float h1s[160 * 68];    // 10880  (chan-inner, padded 68)
    const int t = threadIdx.x;
    const int b = blockIdx.x >> 6, q0 = (blockIdx.x & 63) * 64;
    const float* xb = x + b * 3 * NPTS;
    const int j64 = t & 63, grp = t >> 6;
    float wr[6];
#pragma unroll
    for (int i = 0; i < 6; ++i) wr[i] = w1[j64 * 6 + i];
    const float sc = W[OFF_SC1 + j64], sh = W[OFF_SH1 + j64];
    const int rr = t & 15, cc = t >> 4;
    float acc[4][4];
#pragma unroll
    for (int i = 0; i < 4; ++i)
#pragma unroll
        for (int j = 0; j < 4; ++j) acc[i][j] = 0.f;
    float ssum = 0.f;
    const int ebase = (b * NPTS + q0) * KNN;
    for (int ch = 0; ch < 8; ++ch) {
        __syncthreads();
        if (t < 160) {
            int eg = ch * 160 + t;
            int q = q0 + eg / KNN;
            int jn = idx[ebase + eg];
            float cx = xb[q], cy = xb[NPTS + q], cz = xb[2 * NPTS + q];
            float* E = &eds[t * 6];
            E[0] = cx; E[1] = cy; E[2] = cz;
            E[3] = xb[jn] - cx; E[4] = xb[NPTS + jn] - cy; E[5] = xb[2 * NPTS + jn] - cz;
        }
        __syncthreads();
        for (int e = grp * 40; e < grp * 40 + 40; ++e) {
            const float* E = &eds[e * 6];
            float z = wr[0] * E[0] + wr[1] * E[1] + wr[2] * E[2] + wr[3] * E[3] + wr[4] * E[4] + wr[5] * E[5];
            float h = sc * z + sh;
            h1s[e * 68 + j64] = h > 0.f ? h : 0.f;
        }
        __syncthreads();
#pragma unroll 2
        for (int e = 0; e < 160; ++e) {
            float4 fa = *(const float4*)&h1s[e * 68 + 4 * rr];
            float4 fb = *(const float4*)&h1s[e * 68 + 4 * cc];
            acc[0][0] += fa.x * fb.x; acc[0][1] += fa.x * fb.y; acc[0][2] += fa.x * fb.z; acc[0][3] += fa.x * fb.w;
            acc[1][0] += fa.y * fb.x; acc[1][1] += fa.y * fb.y; acc[1][2] += fa.y * fb.z; acc[1][3] += fa.y * fb.w;
            acc[2][0] += fa.z * fb.x; acc[2][1] += fa.z * fb.y; acc[2][2] += fa.z * fb.z; acc[2][3] += fa.z * fb.w;
            acc[3][0] += fa.w * fb.x; acc[3][1] += fa.w * fb.y; acc[3][2] += fa.w * fb.z; acc[3][3] += fa.w * fb.w;
        }
        for (int e = grp; e < 160; e += 4) ssum += h1s[e * 68 + j64];
    }
    const int part = blockIdx.x & 3;
    float* Gp = &W[OFF_G1P + part * 4096];
#pragma unroll
    for (int i = 0; i < 4; ++i)
#pragma unroll
        for (int j = 0; j < 4; ++j)
            atomicAdd(&Gp[(4 * rr + i) * 64 + 4 * cc + j], acc[i][j]);
    atomicAdd(&W[OFF_S1P + part * 64 + j64], ssum);
}

// bn2 affine from Gram: var(w2_c·h1) = w2_c G w2_c^T/CNT - mean^2
__global__ __launch_bounds__(256) void k_fin2(const float* __restrict__ w2, const float* __restrict__ g2,
                                              const float* __restrict__ b2, float* W) {
    __shared__ float Gs[4096];
    __shared__ float s1s[64];
    __shared__ float w2s[128 * 65];
    const int t = threadIdx.x;
    for (int i = t; i < 4096; i += 256)
        Gs[i] = W[OFF_G1P + i] + W[OFF_G1P + 4096 + i] + W[OFF_G1P + 8192 + i] + W[OFF_G1P + 12288 + i];
    if (t < 64) s1s[t] = W[OFF_S1P + t] + W[OFF_S1P + 64 + t] + W[OFF_S1P + 128 + t] + W[OFF_S1P + 192 + t];
    for (int i = t; i < 8192; i += 256) w2s[(i >> 6) * 65 + (i & 63)] = w2[i];
    __syncthreads();
    const int c = t >> 1, half = t & 1;
    float acc = 0.f;
    for (int ii = 0; ii < 32; ++ii) {
        int i = 32 * half + ii;
        float wi = w2s[c * 65 + i];
        float inner = 0.f;
        for (int j = 0; j < 64; ++j) inner += Gs[i * 64 + j] * w2s[c * 65 + j];
        acc += wi * inner;
    }
    acc += __shfl_xor(acc, 1);
    if (half == 0) {
        float ms = 0.f;
        for (int j = 0; j < 64; ++j) ms += w2s[c * 65 + j] * s1s[j];
        float mean = ms * (1.f / CNT1f);
        float var = acc * (1.f / CNT1f) - mean * mean;
        float sc = g2[c] * rsqrtf(var + BNEPS);
        W[OFF_SC2 + c] = sc;
        W[OFF_SH2 + c] = b2[c] - mean * sc;
    }
}

// -------- pass B: conv1+bn1+relu -> conv2+bn2+relu -> max over K -> M --------
__global__ __launch_bounds__(320) void k_c2apply(const float* __restrict__ x, const int* __restrict__ idx,
                                                 const float* __restrict__ w1, const float* __restrict__ w2,
                                                 float* W) {
    __shared__ float w2t[64 * 132];       // [j][chan], padded
    __shared__ float h1t[64 * 84];        // [j][edge], padded
    __shared__ float eds[80 * 6];
    __shared__ unsigned int maxb[4 * 128];
    const int t = threadIdx.x;
    const int b = blockIdx.y, q0 = blockIdx.x * 4;
    const float* xb = x + b * 3 * NPTS;
    const int ebase = (b * NPTS + q0) * KNN;
    for (int i = t; i < 8192; i += 320) w2t[(i & 63) * 132 + (i >> 6)] = w2[i];
    if (t < 80) {
        int q = q0 + t / KNN;
        int jn = idx[ebase + t];
        float cx = xb[q], cy = xb[NPTS + q], cz = xb[2 * NPTS + q];
        float* E = &eds[t * 6];
        E[0] = cx; E[1] = cy; E[2] = cz;
        E[3] = xb[jn] - cx; E[4] = xb[NPTS + jn] - cy; E[5] = xb[2 * NPTS + jn] - cz;
    }
    for (int i = t; i < 512; i += 320) maxb[i] = 0u;
    __syncthreads();
    {
        const int j64 = t & 63, grp = t >> 6;   // grp 0..4
        float wr[6];
#pragma unroll
        for (int i = 0; i < 6; ++i) wr[i] = w1[j64 * 6 + i];
        const float sc = W[OFF_SC1 + j64], sh = W[OFF_SH1 + j64];
        for (int e = grp * 16; e < grp * 16 + 16; ++e) {
            const float* E = &eds[e * 6];
            float z = wr[0] * E[0] + wr[1] * E[1] + wr[2] * E[2] + wr[3] * E[3] + wr[4] * E[4] + wr[5] * E[5];
            float h = sc * z + sh;
            h1t[j64 * 84 + e] = h > 0.f ? h : 0.f;
        }
    }
    __syncthreads();
    const int cg = t & 31, slot = t >> 5;   // 32 chan-groups x 10 slots
    float sc2[4], sh2[4];
#pragma unroll
    for (int c = 0; c < 4; ++c) { sc2[c] = W[OFF_SC2 + 4 * cg + c]; sh2[c] = W[OFF_SH2 + 4 * cg + c]; }
    for (int it = 0; it < 2; ++it) {
        int g = it * 10 + slot;            // 0..19
        int q = g / 5, kp = g - 5 * q;
        int e0 = q * 20 + 4 * kp;
        float a0x = 0.f, a0y = 0.f, a0z = 0.f, a0w = 0.f;
        float a1x = 0.f, a1y = 0.f, a1z = 0.f, a1w = 0.f;
        float a2x = 0.f, a2y = 0.f, a2z = 0.f, a2w = 0.f;
        float a3x = 0.f, a3y = 0.f, a3z = 0.f, a3w = 0.f;
#pragma unroll 4
        for (int j = 0; j < 64; ++j) {
            float4 wvv = *(const float4*)&w2t[j * 132 + 4 * cg];
            float4 hv = *(const float4*)&h1t[j * 84 + e0];
            a0x += hv.x * wvv.x; a0y += hv.x * wvv.y; a0z += hv.x * wvv.z; a0w += hv.x * wvv.w;
            a1x += hv.y * wvv.x; a1y += hv.y * wvv.y; a1z += hv.y * wvv.z; a1w += hv.y * wvv.w;
            a2x += hv.z * wvv.x; a2y += hv.z * wvv.y; a2z += hv.z * wvv.z; a2w += hv.z * wvv.w;
            a3x += hv.w * wvv.x; a3y += hv.w * wvv.y; a3z += hv.w * wvv.z; a3w += hv.w * wvv.w;
        }
        float em[4];
        em[0] = fmaxf(fmaxf(sc2[0] * a0x + sh2[0], sc2[0] * a1x + sh2[0]),
                      fmaxf(sc2[0] * a2x + sh2[0], sc2[0] * a3x + sh2[0]));
        em[1] = fmaxf(fmaxf(sc2[1] * a0y + sh2[1], sc2[1] * a1y + sh2[1]),
                      fmaxf(sc2[1] * a2y + sh2[1], sc2[1] * a3y + sh2[1]));
        em[2] = fmaxf(fmaxf(sc2[2] * a0z + sh2[2], sc2[2] * a1z + sh2[2]),
                      fmaxf(sc2[2] * a2z + sh2[2], sc2[2] * a3z + sh2[2]));
        em[3] = fmaxf(fmaxf(sc2[3] * a0w + sh2[3], sc2[3] * a1w + sh2[3]),
                      fmaxf(sc2[3] * a2w + sh2[3], sc2[3] * a3w + sh2[3]));
#pragma unroll
        for (int c = 0; c < 4; ++c) {
            float v = em[c] > 0.f ? em[c] : 0.f;
            atomicMax(&maxb[q * 128 + 4 * cg + c], __float_as_uint(v));
        }
    }
    __syncthreads();
    if (t < 128) {
        int q = t >> 5, c4 = t & 31;
        float4 o;
        o.x = __uint_as_float(maxb[q * 128 + 4 * c4 + 0]);
        o.y = __uint_as_float(maxb[q * 128 + 4 * c4 + 1]);
        o.z = __uint_as_float(maxb[q * 128 + 4 * c4 + 2]);
        o.w = __uint_as_float(maxb[q * 128 + 4 * c4 + 3]);
        *(float4*)&W[OFF_M + (b * NPTS + q0 + q) * 128 + 4 * c4] = o;
    }
}

// -------- G3 = M^T M (128x128) and Sum(m) for bn3 ---------------------------
__global__ __launch_bounds__(256) void k_gram3(float* W) {
    __shared__ float Ms[64 * 132];
    const int t = threadIdx.x;
    const int rg = t & 15, cg = t >> 4;
    const int r0 = blockIdx.x * 512;
    const float* M = &W[OFF_M];
    float acc[8][8];
#pragma unroll
    for (int i = 0; i < 8; ++i)
#pragma unroll
        for (int j = 0; j < 8; ++j) acc[i][j] = 0.f;
    float smacc = 0.f;
    for (int ch = 0; ch < 8; ++ch) {
        __syncthreads();
        for (int i = t; i < 8192; i += 256)
            Ms[(i >> 7) * 132 + (i & 127)] = M[(r0 + ch * 64) * 128 + i];
        __syncthreads();
#pragma unroll 2
        for (int e = 0; e < 64; ++e) {
            float4 x0 = *(const float4*)&Ms[e * 132 + 8 * rg];
            float4 x1 = *(const float4*)&Ms[e * 132 + 8 * rg + 4];
            float4 y0 = *(const float4*)&Ms[e * 132 + 8 * cg];
            float4 y1 = *(const float4*)&Ms[e * 132 + 8 * cg + 4];
            float av[8] = {x0.x, x0.y, x0.z, x0.w, x1.x, x1.y, x1.z, x1.w};
            float bv[8] = {y0.x, y0.y, y0.z, y0.w, y1.x, y1.y, y1.z, y1.w};
#pragma unroll
            for (int i = 0; i < 8; ++i)
#pragma unroll
                for (int j = 0; j < 8; ++j) acc[i][j] += av[i] * bv[j];
        }
        if (t < 128) {
            float s = 0.f;
            for (int e = 0; e < 64; ++e) s += Ms[e * 132 + t];
            smacc += s;
        }
    }
    const int part = blockIdx.x & 1;
    float* Gp = &W[OFF_G3P + part * 16384];
#pragma unroll
    for (int i = 0; i < 8; ++i)
#pragma unroll
        for (int j = 0; j < 8; ++j)
            atomicAdd(&Gp[(8 * rg + i) * 128 + 8 * cg + j], acc[i][j]);
    if (t < 128) atomicAdd(&W[OFF_SM3P + part * 128 + t], smacc);
}

// bn3 affine: 16 channels per block
__global__ __launch_bounds__(256) void k_fin3(const float* __restrict__ w3, const float* __restrict__ g3,
                                              const float* __restrict__ b3, float* W) {
    __shared__ float G3s[128 * 129];
    __shared__ float w3s[16 * 132];
    __shared__ float sm3[128];
    __shared__ float red[256];
    __shared__ float mred[16];
    const int t = threadIdx.x;
    const int c0 = blockIdx.x * 16;
    for (int i = t; i < 16384; i += 256)
        G3s[(i >> 7) * 129 + (i & 127)] = W[OFF_G3P + i] + W[OFF_G3P + 16384 + i];
    for (int i = t; i < 2048; i += 256)
        w3s[(i >> 7) * 132 + (i & 127)] = w3[(c0 + (i >> 7)) * 128 + (i & 127)];
    if (t < 128) sm3[t] = W[OFF_SM3P + t] + W[OFF_SM3P + 128 + t];
    __syncthreads();
    const int cl = t >> 4, seg = t & 15;
    float acc = 0.f;
    for (int ii = 0; ii < 8; ++ii) {
        int i = 8 * seg + ii;
        float wi = w3s[cl * 132 + i];
        float inner = 0.f;
        for (int j = 0; j < 128; ++j) inner += G3s[i * 129 + j] * w3s[cl * 132 + j];
        acc += wi * inner;
    }
    red[t] = acc;
    if (seg == 0) {
        float ms = 0.f;
        for (int j = 0; j < 128; ++j) ms += w3s[cl * 132 + j] * sm3[j];
        mred[cl] = ms;
    }
    __syncthreads();
    if (t < 16) {
        float s = 0.f;
#pragma unroll
        for (int k = 0; k < 16; ++k) s += red[t * 16 + k];
        float mean = mred[t] * (1.f / CNT3f);
        float var = s * (1.f / CNT3f) - mean * mean;
        float sc = g3[c0 + t] * rsqrtf(var + BNEPS);
        W[OFF_SC3 + c0 + t] = sc;
        W[OFF_SH3 + c0 + t] = b3[c0 + t] - mean * sc;
    }
}

// -------- conv3 apply: z3 = M @ w3^T, bn3+relu, max over N -> GMAX ----------
__global__ __launch_bounds__(256) void k_conv3(const float* __restrict__ w3, float* W) {
    __shared__ float mt[64 * 68];
    __shared__ float w3s[64 * 68];
    __shared__ float red[16 * 68];
    const int p0 = blockIdx.x * 64, c0 = blockIdx.y * 64;
    const int t = threadIdx.x, tr = t & 15, tc = t >> 4;
    float acc[4][4];
#pragma unroll
    for (int i = 0; i < 4; ++i)
#pragma unroll
        for (int c = 0; c < 4; ++c) acc[i][c] = 0.f;
    const float* M = &W[OFF_M];
    for (int kt = 0; kt < 2; ++kt) {
        if (kt) __syncthreads();
        for (int i = t; i < 8192; i += 256) {
            int p = i >> 6, j = i & 63;
            mt[p * 68 + j] = M[(p0 + p) * 128 + kt * 64 + j];
            w3s[p * 68 + j] = w3[(c0 + p) * 128 + kt * 64 + j];
        }
        __syncthreads();
        for (int jt = 0; jt < 16; ++jt) {
            float4 A[4], Bv[4];
#pragma unroll
            for (int i = 0; i < 4; ++i) A[i] = *(const float4*)&mt[(tr + 16 * i) * 68 + 4 * jt];
#pragma unroll
            for (int c = 0; c < 4; ++c) Bv[c] = *(const float4*)&w3s[(4 * tc + c) * 68 + 4 * jt];
#pragma unroll
            for (int i = 0; i < 4; ++i)
#pragma unroll
                for (int c = 0; c < 4; ++c)
                    acc[i][c] += A[i].x * Bv[c].x + A[i].y * Bv[c].y + A[i].z * Bv[c].z + A[i].w * Bv[c].w;
        }
    }
    __syncthreads();
    const int bb = p0 >> 12;
#pragma unroll
    for (int c = 0; c < 4; ++c) {
        int chn = c0 + 4 * tc + c;
        float sc = W[OFF_SC3 + chn], sh = W[OFF_SH3 + chn];
        float mx = 0.f;
#pragma unroll
        for (int i = 0; i < 4; ++i) {
            float h = sc * acc[i][c] + sh;
            mx = fmaxf(mx, h > 0.f ? h : 0.f);
        }
        red[tr * 68 + 4 * tc + c] = mx;
    }
    __syncthreads();
    if (t < 64) {
        float mx = 0.f;
        for (int r = 0; r < 16; ++r) mx = fmaxf(mx, red[r * 68 + t]);
        atomicMax((unsigned int*)&W[OFF_GMAX + bb * 1024 + c0 + t], __float_as_uint(mx));
    }
}

// -------- z4 = gmax(8x1024) @ w4^T(512x1024) --------------------------------
__global__ __launch_bounds__(256) void k_fc4(const float* __restrict__ w4, float* W) {
    __shared__ float red[256];
    const int t = threadIdx.x;
    const int oidx = t >> 3, s = t & 7;
    const int cc = oidx >> 3, b = oidx & 7;
    const int c = blockIdx.x * 4 + cc;
    const float* g = &W[OFF_GMAX];
    const float* wr = &w4[c * 1024 + s * 128];
    const float* gr = &g[b * 1024 + s * 128];
    float p = 0.f;
    for (int j = 0; j < 128; ++j) p += wr[j] * gr[j];
    red[t] = p;
    __syncthreads();
    if (t < 32) {
        float tot = 0.f;
        for (int k = 0; k < 8; ++k) tot += red[t * 8 + k];
        W[OFF_Z4 + (t & 7) * 512 + blockIdx.x * 4 + (t >> 3)] = tot;
    }
}

// -------- tail: bn4+relu, fc5, bn5+relu, final linear + eye -----------------
__global__ __launch_bounds__(512) void k_tail(const float* __restrict__ g4, const float* __restrict__ b4,
                                              const float* __restrict__ w5, const float* __restrict__ g5,
                                              const float* __restrict__ b5, const float* __restrict__ wl,
                                              const float* __restrict__ bl, float* W, float* __restrict__ out) {
    __shared__ float h4L[8 * 512];
    __shared__ float w5s[2 * 256 * 9];
    __shared__ float zp[2 * 2048];
    const int t = threadIdx.x;
    {
        float v[8]; float s = 0.f, q = 0.f;
#pragma unroll
        for (int b = 0; b < 8; ++b) { v[b] = W[OFF_Z4 + b * 512 + t]; s += v[b]; q += v[b] * v[b]; }
        float mean = s * 0.125f;
        float var = q * 0.125f - mean * mean;
        float sc = g4[t] * rsqrtf(var + BNEPS);
        float sh = b4[t] - mean * sc;
#pragma unroll
        for (int b = 0; b < 8; ++b) {
            float h = sc * v[b] + sh;
            h4L[b * 512 + t] = h > 0.f ? h : 0.f;
        }
    }
    const int c5 = t & 255, half = t >> 8;
    float acc[8];
#pragma unroll
    for (int b = 0; b < 8; ++b) acc[b] = 0.f;
    for (int jt = 0; jt < 32; ++jt) {
        __syncthreads();
        for (int i = t; i < 4096; i += 512) {
            int h = i >> 11, rem = i & 2047;
            int ci = rem >> 3, jj = rem & 7;
            w5s[h * 2304 + ci * 9 + jj] = w5[ci * 512 + h * 256 + jt * 8 + jj];
        }
        __syncthreads();
#pragma unroll
        for (int jj = 0; jj < 8; ++jj) {
            float wv = w5s[half * 2304 + c5 * 9 + jj];
            int jg = half * 256 + jt * 8 + jj;
#pragma unroll
            for (int b = 0; b < 8; ++b) acc[b] += wv * h4L[b * 512 + jg];
        }
    }
#pragma unroll
    for (int b = 0; b < 8; ++b) zp[half * 2048 + b * 256 + c5] = acc[b];
    __syncthreads();
    if (t < 256) {
        float v[8], s = 0.f, q = 0.f;
#pragma unroll
        for (int b = 0; b < 8; ++b) {
            v[b] = zp[b * 256 + t] + zp[2048 + b * 256 + t];
            s += v[b]; q += v[b] * v[b];
        }
        float mean = s * 0.125f, var = q * 0.125f - mean * mean;
        float sc = g5[t] * rsqrtf(var + BNEPS), sh = b5[t] - mean * sc;
#pragma unroll
        for (int b = 0; b < 8; ++b) { float h = sc * v[b] + sh; zp[b * 256 + t] = h > 0.f ? h : 0.f; }
    }
    __syncthreads();
    if (t < 72) {
        int b = t / 9, r = t % 9;
        float a = bl[r] + ((r == 0 || r == 4 || r == 8) ? 1.f : 0.f);
        for (int j = 0; j < 256; ++j) a += wl[r * 256 + j] * zp[b * 256 + j];
        out[b * 9 + r] = a;
    }
}

extern "C" void kernel_launch(void* const* d_in, const int* in_sizes, int n_in,
                              void* d_out, int out_size, void* d_ws, size_t ws_size,
                              hipStream_t stream) {
    const float* x  = (const float*)d_in[0];
    const float* w1 = (const float*)d_in[1];
    const float* g1 = (const float*)d_in[2];
    const float* b1 = (const float*)d_in[3];
    const float* w2 = (const float*)d_in[4];
    const float* g2 = (const float*)d_in[5];
    const float* b2 = (const float*)d_in[6];
    const float* w3 = (const float*)d_in[7];
    const float* g3 = (const float*)d_in[8];
    const float* b3 = (const float*)d_in[9];
    const float* w4 = (const float*)d_in[10];
    const float* g4 = (const float*)d_in[11];
    const float* b4 = (const float*)d_in[12];
    const float* w5 = (const float*)d_in[13];
    const float* g5 = (const float*)d_in[14];
    const float* b5 = (const float*)d_in[15];
    const float* wl = (const float*)d_in[16];
    const float* bl = (const float*)d_in[17];
    float* W = (float*)d_ws;
    int* idx = (int*)d_ws;
    float* out = (float*)d_out;

    k_init<<<dim3(69), dim3(256), 0, stream>>>(W, ZERO1_BEG, ZERO1_CNT);
    k_knn<<<dim3(1024, 8), dim3(256), 0, stream>>>(x, idx, W);
    k_fin1<<<dim3(1), dim3(64), 0, stream>>>(w1, g1, b1, W);
    k_gram1<<<dim3(512), dim3(256), 0, stream>>>(x, idx, w1, W);
    k_fin2<<<dim3(1), dim3(256), 0, stream>>>(w2, g2, b2, W);
    k_c2apply<<<dim3(1024, 8), dim3(320), 0, stream>>>(x, idx, w1, w2, W);
    k_init<<<dim3(161), dim3(256), 0, stream>>>(W, ZERO2_BEG, ZERO2_CNT);
    k_gram3<<<dim3(64), dim3(256), 0, stream>>>(W);
    k_fin3<<<dim3(64), dim3(256), 0, stream>>>(w3, g3, b3, W);
    k_conv3<<<dim3(512, 16), dim3(256), 0, stream>>>(w3, W);
    k_fc4<<<dim3(128), dim3(256), 0, stream>>>(w4, W);
    k_tail<<<dim3(1), dim3(512), 0, stream>>>(g4, b4, w5, g5, b5, wl, bl, W, out);
}

// Round 4
// 1164.991 us; speedup vs baseline: 17.2303x; 1.1439x over previous
//
#include <hip/hip_runtime.h>

#define NPTS 4096
#define KNN 20
#define CNT1f 655360.0f   // B*N*K
#define CNT3f 32768.0f    // B*N
#define BNEPS 1e-5f

// ---- workspace layout (float offsets into d_ws) ----
// Phase aliasing: [idx region 0..655360) holds idx until k_c2apply is done,
// then is reused for G3/SM3/GMAX/Z4. [M region 655360..4849664) holds the
// phase-1 stats accumulators until fin2, then M overwrites them.
#define OFF_IDX   0
#define OFF_G3P   0          // 2*16384   (alias, after c2apply)
#define OFF_SM3P  32768      // 2*128
#define OFF_GMAX  33024      // 8*1024
#define OFF_Z4    41216      // 8*512
#define OFF_M     655360     // 32768*128
#define OFF_ES    655360     // 32 partials x 32 (27 used)  (alias, pre-c2apply)
#define OFF_G1P   656384     // 4*4096
#define OFF_S1P   672768     // 4*64
#define ZERO1_BEG 655360
#define ZERO1_CNT 17664
#define ZERO2_BEG 0
#define ZERO2_CNT 41216
#define OFF_SC1   4849664
#define OFF_SH1   4849728
#define OFF_SC2   4849792
#define OFF_SH2   4849920
#define OFF_SC3   4850048
#define OFF_SH3   4851072

__global__ __launch_bounds__(256) void k_init(float* W, int beg, int cnt) {
    int i = blockIdx.x * 256 + threadIdx.x;
    if (i < cnt) W[beg + i] = 0.0f;
}

// ---- wave-wide: find bin B containing the K-th smallest (1-indexed) in H ----
template <int PER>
__device__ __forceinline__ void wave_scan_find(const int* H, int K, int lane,
                                               int& B, int& below, int& hB) {
    int c[PER]; int s = 0;
    const int base = lane * PER;
#pragma unroll
    for (int p = 0; p < PER; ++p) { c[p] = H[base + p]; s += c[p]; }
    int pre = s;
#pragma unroll
    for (int off = 1; off < 64; off <<= 1) {
        int t = __shfl_up(pre, off, 64);
        if (lane >= off) pre += t;
    }
    int excl = pre - s;
    bool has = (excl < K) && (K <= excl + s);
    unsigned long long m = __ballot(has);
    int src = (int)(__ffsll((unsigned long long)m) - 1);
    int mb = 0, mbelow = 0, mh = 0;
    if (lane == src) {
        int cum = excl;
#pragma unroll
        for (int p = 0; p < PER; ++p) {
            if (cum < K && K <= cum + c[p]) { mb = base + p; mbelow = cum; mh = c[p]; break; }
            cum += c[p];
        }
    }
    B = __shfl(mb, src, 64);
    below = __shfl(mbelow, src, 64);
    hB = __shfl(mh, src, 64);
}

// -------- KNN via radix-select: 1 wave/query, 4 queries/block ---------------
// Keys (float bits of d^2) cached in 64 VGPRs/lane: distances computed ONCE.
// 3 levels x 8 bits (256-bin hist) -> 24-bit threshold; early exit when the
// boundary bin count exactly matches the remainder. Downstream consumers are
// order-invariant so only the top-20 SET matters.
__global__ __launch_bounds__(256) void k_knn(const float* __restrict__ x, int* __restrict__ idx, float* W) {
    __shared__ float px[NPTS], py[NPTS], pz[NPTS];   // 48 KB
    __shared__ int hist[4][256];                     // 4 KB
    __shared__ int outi[4][20];
    __shared__ int cnts[4][2];
    __shared__ float estat[27];
    const int tid = threadIdx.x;
    const int b = blockIdx.y;
    const float* xb = x + b * 3 * NPTS;
    for (int i = tid; i < NPTS; i += 256) {
        px[i] = xb[i]; py[i] = xb[NPTS + i]; pz[i] = xb[2 * NPTS + i];
    }
    if (tid < 27) estat[tid] = 0.f;
    if (tid < 8) cnts[tid >> 1][tid & 1] = 0;
    __syncthreads();
    const int wv = tid >> 6, lane = tid & 63;
    const int q = blockIdx.x * 4 + wv;
    const float qx = px[q], qy = py[q], qz = pz[q];
    int* H = hist[wv];
    unsigned int key[64];
#pragma unroll
    for (int p = 0; p < 4; ++p) H[lane * 4 + p] = 0;
#pragma unroll
    for (int it = 0; it < 64; ++it) {
        int j = it * 64 + lane;
        float dx = px[j] - qx, dy = py[j] - qy, dz = pz[j] - qz;
        float d = fmaf(dx, dx, fmaf(dy, dy, dz * dz));
        unsigned int u = __float_as_uint(d);
        key[it] = u;
        atomicAdd(&H[u >> 23], 1);   // d>=0 so uint order == float order; bin < 256
    }
    int B, below, hB;
    wave_scan_find<4>(H, KNN, lane, B, below, hB);
    unsigned int P = (unsigned int)B;
    int rem = KNN - below;
    int S = 23;
    if (hB != rem) {
#pragma unroll
        for (int p = 0; p < 4; ++p) H[lane * 4 + p] = 0;
#pragma unroll
        for (int it = 0; it < 64; ++it) {
            unsigned int u = key[it];
            if ((u >> 23) == P) atomicAdd(&H[(u >> 15) & 255], 1);
        }
        wave_scan_find<4>(H, rem, lane, B, below, hB);
        P = (P << 8) | (unsigned int)B;
        rem -= below;
        S = 15;
        if (hB != rem) {
#pragma unroll
            for (int p = 0; p < 4; ++p) H[lane * 4 + p] = 0;
#pragma unroll
            for (int it = 0; it < 64; ++it) {
                unsigned int u = key[it];
                if ((u >> 15) == P) atomicAdd(&H[(u >> 7) & 255], 1);
            }
            wave_scan_find<4>(H, rem, lane, B, below, hB);
            P = (P << 8) | (unsigned int)B;
            rem -= below;
            S = 7;
        }
    }
    // compact from cached keys: all < P, plus first `rem` == P
    int* OC = cnts[wv];
#pragma unroll
    for (int it = 0; it < 64; ++it) {
        unsigned int k = key[it] >> S;
        if (k <= P) {
            bool take = true;
            if (k == P) { int e = atomicAdd(&OC[1], 1); take = (e < rem); }
            if (take) { int pos = atomicAdd(&OC[0], 1); outi[wv][pos] = it * 64 + lane; }
        }
    }
    const int obase = (b * NPTS + q) * KNN;
    if (lane < KNN) idx[obase + lane] = outi[wv][lane];
    // fused edge moments for bn1: Sum(e) [6] + upper-tri Sum(e e^T) [21]
    float st[27];
#pragma unroll
    for (int v = 0; v < 27; ++v) st[v] = 0.f;
    if (lane < KNN) {
        int j = outi[wv][lane];
        float e[6];
        e[0] = qx; e[1] = qy; e[2] = qz;
        e[3] = px[j] - qx; e[4] = py[j] - qy; e[5] = pz[j] - qz;
        int id = 6;
#pragma unroll
        for (int i = 0; i < 6; ++i) {
            st[i] = e[i];
#pragma unroll
            for (int jj = i; jj < 6; ++jj) { st[id] = e[i] * e[jj]; id++; }
        }
    }
#pragma unroll
    for (int v = 0; v < 27; ++v) {
        float s = st[v];
        s += __shfl_xor(s, 32); s += __shfl_xor(s, 16); s += __shfl_xor(s, 8);
        s += __shfl_xor(s, 4);  s += __shfl_xor(s, 2);  s += __shfl_xor(s, 1);
        st[v] = s;
    }
    if (lane == 0) {
#pragma unroll
        for (int v = 0; v < 27; ++v) atomicAdd(&estat[v], st[v]);
    }
    __syncthreads();
    if (tid < 27) atomicAdd(&W[OFF_ES + (blockIdx.x & 31) * 32 + tid], estat[tid]);
}

// bn1 affine from edge moments: var(w·e) = w E2 w^T /CNT - (w·S/CNT)^2
__global__ void k_fin1(const float* __restrict__ w1, const float* __restrict__ g1,
                       const float* __restrict__ b1, float* W) {
    __shared__ float es[27];
    const int c = threadIdx.x;
    if (c < 27) {
        float s = 0.f;
        for (int p = 0; p < 32; ++p) s += W[OFF_ES + p * 32 + c];
        es[c] = s;
    }
    __syncthreads();
    float wr[6];
#pragma unroll
    for (int i = 0; i < 6; ++i) wr[i] = w1[c * 6 + i];
    float m = 0.f;
#pragma unroll
    for (int i = 0; i < 6; ++i) m += wr[i] * es[i];
    m *= (1.f / CNT1f);
    float qv = 0.f;
    int id = 6;
#pragma unroll
    for (int i = 0; i < 6; ++i)
#pragma unroll
        for (int jj = 0; jj < 6; ++jj)
            if (jj >= i) { qv += (jj == i ? 1.f : 2.f) * wr[i] * wr[jj] * es[id]; id++; }
    qv *= (1.f / CNT1f);
    float var = qv - m * m;
    float sc = g1[c] * rsqrtf(var + BNEPS);
    W[OFF_SC1 + c] = sc;
    W[OFF_SH1 + c] = b1[c] - m * sc;
}

// -------- pass A: accumulate Sum(h1) and G1 = Sum(h1 h1^T) over all edges ----
__global__ __launch_bounds__(256) void k_gram1(const float* __restrict__ x, const int* __restrict__ idx,
                                               const float* __restrict__ w1, float* W) {
    __shared__ float eds[160 * 6];     // 960
    __shared__ float h1s[160 * 68];    // 10880  (chan-inner, padded 68)
    const int t = threadIdx.x;
    const int b = blockIdx.x >> 6, q0 = (blockIdx.x & 63) * 64;
    const float* xb = x + b * 3 * NPTS;
    const int j64 = t & 63, grp = t >> 6;
    float wr[6];
#pragma unroll
    for (int i = 0; i < 6; ++i) wr[i] = w1[j64 * 6 + i];
    const float sc = W[OFF_SC1 + j64], sh = W[OFF_SH1 + j64];
    const int rr = t & 15, cc = t >> 4;
    float acc[4][4];
#pragma unroll
    for (int i = 0; i < 4; ++i)
#pragma unroll
        for (int j = 0; j < 4; ++j) acc[i][j] = 0.f;
    float ssum = 0.f;
    const int ebase = (b * NPTS + q0) * KNN;
    for (int ch = 0; ch < 8; ++ch) {
        __syncthreads();
        if (t < 160) {
            int eg = ch * 160 + t;
            int q = q0 + eg / KNN;
            int jn = idx[ebase + eg];
            float cx = xb[q], cy = xb[NPTS + q], cz = xb[2 * NPTS + q];
            float* E = &eds[t * 6];
            E[0] = cx; E[1] = cy; E[2] = cz;
            E[3] = xb[jn] - cx; E[4] = xb[NPTS + jn] - cy; E[5] = xb[2 * NPTS + jn] - cz;
        }
        __syncthreads();
        for (int e = grp * 40; e < grp * 40 + 40; ++e) {
            const float* E = &eds[e * 6];
            float z = wr[0] * E[0] + wr[1] * E[1] + wr[2] * E[2] + wr[3] * E[3] + wr[4] * E[4] + wr[5] * E[5];
            float h = sc * z + sh;
            h1s[e * 68 + j64] = h > 0.f ? h : 0.f;
        }
        __syncthreads();
#pragma unroll 2
        for (int e = 0; e < 160; ++e) {
            float4 fa = *(const float4*)&h1s[e * 68 + 4 * rr];
            float4 fb = *(const float4*)&h1s[e * 68 + 4 * cc];
            acc[0][0] += fa.x * fb.x; acc[0][1] += fa.x * fb.y; acc[0][2] += fa.x * fb.z; acc[0][3] += fa.x * fb.w;
            acc[1][0] += fa.y * fb.x; acc[1][1] += fa.y * fb.y; acc[1][2] += fa.y * fb.z; acc[1][3] += fa.y * fb.w;
            acc[2][0] += fa.z * fb.x; acc[2][1] += fa.z * fb.y; acc[2][2] += fa.z * fb.z; acc[2][3] += fa.z * fb.w;
            acc[3][0] += fa.w * fb.x; acc[3][1] += fa.w * fb.y; acc[3][2] += fa.w * fb.z; acc[3][3] += fa.w * fb.w;
        }
        for (int e = grp; e < 160; e += 4) ssum += h1s[e * 68 + j64];
    }
    const int part = blockIdx.x & 3;
    float* Gp = &W[OFF_G1P + part * 4096];
#pragma unroll
    for (int i = 0; i < 4; ++i)
#pragma unroll
        for (int j = 0; j < 4; ++j)
            atomicAdd(&Gp[(4 * rr + i) * 64 + 4 * cc + j], acc[i][j]);
    atomicAdd(&W[OFF_S1P + part * 64 + j64], ssum);
}

// bn2 affine from Gram: var(w2_c·h1) = w2_c G w2_c^T/CNT - mean^2
__global__ __launch_bounds__(256) void k_fin2(const float* __restrict__ w2, const float* __restrict__ g2,
                                              const float* __restrict__ b2, float* W) {
    __shared__ float Gs[4096];
    __shared__ float s1s[64];
    __shared__ float w2s[128 * 65];
    const int t = threadIdx.x;
    for (int i = t; i < 4096; i += 256)
        Gs[i] = W[OFF_G1P + i] + W[OFF_G1P + 4096 + i] + W[OFF_G1P + 8192 + i] + W[OFF_G1P + 12288 + i];
    if (t < 64) s1s[t] = W[OFF_S1P + t] + W[OFF_S1P + 64 + t] + W[OFF_S1P + 128 + t] + W[OFF_S1P + 192 + t];
    for (int i = t; i < 8192; i += 256) w2s[(i >> 6) * 65 + (i & 63)] = w2[i];
    __syncthreads();
    const int c = t >> 1, half = t & 1;
    float acc = 0.f;
    for (int ii = 0; ii < 32; ++ii) {
        int i = 32 * half + ii;
        float wi = w2s[c * 65 + i];
        float inner = 0.f;
        for (int j = 0; j < 64; ++j) inner += Gs[i * 64 + j] * w2s[c * 65 + j];
        acc += wi * inner;
    }
    acc += __shfl_xor(acc, 1);
    if (half == 0) {
        float ms = 0.f;
        for (int j = 0; j < 64; ++j) ms += w2s[c * 65 + j] * s1s[j];
        float mean = ms * (1.f / CNT1f);
        float var = acc * (1.f / CNT1f) - mean * mean;
        float sc = g2[c] * rsqrtf(var + BNEPS);
        W[OFF_SC2 + c] = sc;
        W[OFF_SH2 + c] = b2[c] - mean * sc;
    }
}

// -------- pass B: conv1+bn1+relu -> conv2+bn2+relu -> max over K -> M --------
__global__ __launch_bounds__(320) void k_c2apply(const float* __restrict__ x, const int* __restrict__ idx,
                                                 const float* __restrict__ w1, const float* __restrict__ w2,
                                                 float* W) {
    __shared__ float w2t[64 * 132];       // [j][chan], padded
    __shared__ float h1t[64 * 84];        // [j][edge], padded
    __shared__ float eds[80 * 6];
    __shared__ unsigned int maxb[4 * 128];
    const int t = threadIdx.x;
    const int b = blockIdx.y, q0 = blockIdx.x * 4;
    const float* xb = x + b * 3 * NPTS;
    const int ebase = (b * NPTS + q0) * KNN;
    for (int i = t; i < 8192; i += 320) w2t[(i & 63) * 132 + (i >> 6)] = w2[i];
    if (t < 80) {
        int q = q0 + t / KNN;
        int jn = idx[ebase + t];
        float cx = xb[q], cy = xb[NPTS + q], cz = xb[2 * NPTS + q];
        float* E = &eds[t * 6];
        E[0] = cx; E[1] = cy; E[2] = cz;
        E[3] = xb[jn] - cx; E[4] = xb[NPTS + jn] - cy; E[5] = xb[2 * NPTS + jn] - cz;
    }
    for (int i = t; i < 512; i += 320) maxb[i] = 0u;
    __syncthreads();
    {
        const int j64 = t & 63, grp = t >> 6;   // grp 0..4
        float wr[6];
#pragma unroll
        for (int i = 0; i < 6; ++i) wr[i] = w1[j64 * 6 + i];
        const float sc = W[OFF_SC1 + j64], sh = W[OFF_SH1 + j64];
        for (int e = grp * 16; e < grp * 16 + 16; ++e) {
            const float* E = &eds[e * 6];
            float z = wr[0] * E[0] + wr[1] * E[1] + wr[2] * E[2] + wr[3] * E[3] + wr[4] * E[4] + wr[5] * E[5];
            float h = sc * z + sh;
            h1t[j64 * 84 + e] = h > 0.f ? h : 0.f;
        }
    }
    __syncthreads();
    const int cg = t & 31, slot = t >> 5;   // 32 chan-groups x 10 slots
    float sc2[4], sh2[4];
#pragma unroll
    for (int c = 0; c < 4; ++c) { sc2[c] = W[OFF_SC2 + 4 * cg + c]; sh2[c] = W[OFF_SH2 + 4 * cg + c]; }
    for (int it = 0; it < 2; ++it) {
        int g = it * 10 + slot;            // 0..19
        int q = g / 5, kp = g - 5 * q;
        int e0 = q * 20 + 4 * kp;
        float a0x = 0.f, a0y = 0.f, a0z = 0.f, a0w = 0.f;
        float a1x = 0.f, a1y = 0.f, a1z = 0.f, a1w = 0.f;
        float a2x = 0.f, a2y = 0.f, a2z = 0.f, a2w = 0.f;
        float a3x = 0.f, a3y = 0.f, a3z = 0.f, a3w = 0.f;
#pragma unroll 4
        for (int j = 0; j < 64; ++j) {
            float4 wvv = *(const float4*)&w2t[j * 132 + 4 * cg];
            float4 hv = *(const float4*)&h1t[j * 84 + e0];
            a0x += hv.x * wvv.x; a0y += hv.x * wvv.y; a0z += hv.x * wvv.z; a0w += hv.x * wvv.w;
            a1x += hv.y * wvv.x; a1y += hv.y * wvv.y; a1z += hv.y * wvv.z; a1w += hv.y * wvv.w;
            a2x += hv.z * wvv.x; a2y += hv.z * wvv.y; a2z += hv.z * wvv.z; a2w += hv.z * wvv.w;
            a3x += hv.w * wvv.x; a3y += hv.w * wvv.y; a3z += hv.w * wvv.z; a3w += hv.w * wvv.w;
        }
        float em[4];
        em[0] = fmaxf(fmaxf(sc2[0] * a0x + sh2[0], sc2[0] * a1x + sh2[0]),
                      fmaxf(sc2[0] * a2x + sh2[0], sc2[0] * a3x + sh2[0]));
        em[1] = fmaxf(fmaxf(sc2[1] * a0y + sh2[1], sc2[1] * a1y + sh2[1]),
                      fmaxf(sc2[1] * a2y + sh2[1], sc2[1] * a3y + sh2[1]));
        em[2] = fmaxf(fmaxf(sc2[2] * a0z + sh2[2], sc2[2] * a1z + sh2[2]),
                      fmaxf(sc2[2] * a2z + sh2[2], sc2[2] * a3z + sh2[2]));
        em[3] = fmaxf(fmaxf(sc2[3] * a0w + sh2[3], sc2[3] * a1w + sh2[3]),
                      fmaxf(sc2[3] * a2w + sh2[3], sc2[3] * a3w + sh2[3]));
#pragma unroll
        for (int c = 0; c < 4; ++c) {
            float v = em[c] > 0.f ? em[c] : 0.f;
            atomicMax(&maxb[q * 128 + 4 * cg + c], __float_as_uint(v));
        }
    }
    __syncthreads();
    if (t < 128) {
        int q = t >> 5, c4 = t & 31;
        float4 o;
        o.x = __uint_as_float(maxb[q * 128 + 4 * c4 + 0]);
        o.y = __uint_as_float(maxb[q * 128 + 4 * c4 + 1]);
        o.z = __uint_as_float(maxb[q * 128 + 4 * c4 + 2]);
        o.w = __uint_as_float(maxb[q * 128 + 4 * c4 + 3]);
        *(float4*)&W[OFF_M + (b * NPTS + q0 + q) * 128 + 4 * c4] = o;
    }
}

// -------- G3 = M^T M (128x128) and Sum(m) for bn3 ---------------------------
__global__ __launch_bounds__(256) void k_gram3(float* W) {
    __shared__ float Ms[64 * 132];
    const int t = threadIdx.x;
    const int rg = t & 15, cg = t >> 4;
    const int r0 = blockIdx.x * 512;
    const float* M = &W[OFF_M];
    float acc[8][8];
#pragma unroll
    for (int i = 0; i < 8; ++i)
#pragma unroll
        for (int j = 0; j < 8; ++j) acc[i][j] = 0.f;
    float smacc = 0.f;
    for (int ch = 0; ch < 8; ++ch) {
        __syncthreads();
        for (int i = t; i < 8192; i += 256)
            Ms[(i >> 7) * 132 + (i & 127)] = M[(r0 + ch * 64) * 128 + i];
        __syncthreads();
#pragma unroll 2
        for (int e = 0; e < 64; ++e) {
            float4 x0 = *(const float4*)&Ms[e * 132 + 8 * rg];
            float4 x1 = *(const float4*)&Ms[e * 132 + 8 * rg + 4];
            float4 y0 = *(const float4*)&Ms[e * 132 + 8 * cg];
            float4 y1 = *(const float4*)&Ms[e * 132 + 8 * cg + 4];
            float av[8] = {x0.x, x0.y, x0.z, x0.w, x1.x, x1.y, x1.z, x1.w};
            float bv[8] = {y0.x, y0.y, y0.z, y0.w, y1.x, y1.y, y1.z, y1.w};
#pragma unroll
            for (int i = 0; i < 8; ++i)
#pragma unroll
                for (int j = 0; j < 8; ++j) acc[i][j] += av[i] * bv[j];
        }
        if (t < 128) {
            float s = 0.f;
            for (int e = 0; e < 64; ++e) s += Ms[e * 132 + t];
            smacc += s;
        }
    }
    const int part = blockIdx.x & 1;
    float* Gp = &W[OFF_G3P + part * 16384];
#pragma unroll
    for (int i = 0; i < 8; ++i)
#pragma unroll
        for (int j = 0; j < 8; ++j)
            atomicAdd(&Gp[(8 * rg + i) * 128 + 8 * cg + j], acc[i][j]);
    if (t < 128) atomicAdd(&W[OFF_SM3P + part * 128 + t], smacc);
}

// bn3 affine: 16 channels per block
__global__ __launch_bounds__(256) void k_fin3(const float* __restrict__ w3, const float* __restrict__ g3,
                                              const float* __restrict__ b3, float* W) {
    __shared__ float G3s[128 * 129];
    __shared__ float w3s[16 * 132];
    __shared__ float sm3[128];
    __shared__ float red[256];
    __shared__ float mred[16];
    const int t = threadIdx.x;
    const int c0 = blockIdx.x * 16;
    for (int i = t; i < 16384; i += 256)
        G3s[(i >> 7) * 129 + (i & 127)] = W[OFF_G3P + i] + W[OFF_G3P + 16384 + i];
    for (int i = t; i < 2048; i += 256)
        w3s[(i >> 7) * 132 + (i & 127)] = w3[(c0 + (i >> 7)) * 128 + (i & 127)];
    if (t < 128) sm3[t] = W[OFF_SM3P + t] + W[OFF_SM3P + 128 + t];
    __syncthreads();
    const int cl = t >> 4, seg = t & 15;
    float acc = 0.f;
    for (int ii = 0; ii < 8; ++ii) {
        int i = 8 * seg + ii;
        float wi = w3s[cl * 132 + i];
        float inner = 0.f;
        for (int j = 0; j < 128; ++j) inner += G3s[i * 129 + j] * w3s[cl * 132 + j];
        acc += wi * inner;
    }
    red[t] = acc;
    if (seg == 0) {
        float ms = 0.f;
        for (int j = 0; j < 128; ++j) ms += w3s[cl * 132 + j] * sm3[j];
        mred[cl] = ms;
    }
    __syncthreads();
    if (t < 16) {
        float s = 0.f;
#pragma unroll
        for (int k = 0; k < 16; ++k) s += red[t * 16 + k];
        float mean = mred[t] * (1.f / CNT3f);
        float var = s * (1.f / CNT3f) - mean * mean;
        float sc = g3[c0 + t] * rsqrtf(var + BNEPS);
        W[OFF_SC3 + c0 + t] = sc;
        W[OFF_SH3 + c0 + t] = b3[c0 + t] - mean * sc;
    }
}

// -------- conv3 apply: z3 = M @ w3^T, bn3+relu, max over N -> GMAX ----------
__global__ __launch_bounds__(256) void k_conv3(const float* __restrict__ w3, float* W) {
    __shared__ float mt[64 * 68];
    __shared__ float w3s[64 * 68];
    __shared__ float red[16 * 68];
    const int p0 = blockIdx.x * 64, c0 = blockIdx.y * 64;
    const int t = threadIdx.x, tr = t & 15, tc = t >> 4;
    float acc[4][4];
#pragma unroll
    for (int i = 0; i < 4; ++i)
#pragma unroll
        for (int c = 0; c < 4; ++c) acc[i][c] = 0.f;
    const float* M = &W[OFF_M];
    for (int kt = 0; kt < 2; ++kt) {
        if (kt) __syncthreads();
        for (int i = t; i < 8192; i += 256) {
            int p = i >> 6, j = i & 63;
            mt[p * 68 + j] = M[(p0 + p) * 128 + kt * 64 + j];
            w3s[p * 68 + j] = w3[(c0 + p) * 128 + kt * 64 + j];
        }
        __syncthreads();
        for (int jt = 0; jt < 16; ++jt) {
            float4 A[4], Bv[4];
#pragma unroll
            for (int i = 0; i < 4; ++i) A[i] = *(const float4*)&mt[(tr + 16 * i) * 68 + 4 * jt];
#pragma unroll
            for (int c = 0; c < 4; ++c) Bv[c] = *(const float4*)&w3s[(4 * tc + c) * 68 + 4 * jt];
#pragma unroll
            for (int i = 0; i < 4; ++i)
#pragma unroll
                for (int c = 0; c < 4; ++c)
                    acc[i][c] += A[i].x * Bv[c].x + A[i].y * Bv[c].y + A[i].z * Bv[c].z + A[i].w * Bv[c].w;
        }
    }
    __syncthreads();
    const int bb = p0 >> 12;
#pragma unroll
    for (int c = 0; c < 4; ++c) {
        int chn = c0 + 4 * tc + c;
        float sc = W[OFF_SC3 + chn], sh = W[OFF_SH3 + chn];
        float mx = 0.f;
#pragma unroll
        for (int i = 0; i < 4; ++i) {
            float h = sc * acc[i][c] + sh;
            mx = fmaxf(mx, h > 0.f ? h : 0.f);
        }
        red[tr * 68 + 4 * tc + c] = mx;
    }
    __syncthreads();
    if (t < 64) {
        float mx = 0.f;
        for (int r = 0; r < 16; ++r) mx = fmaxf(mx, red[r * 68 + t]);
        atomicMax((unsigned int*)&W[OFF_GMAX + bb * 1024 + c0 + t], __float_as_uint(mx));
    }
}

// -------- z4 = gmax(8x1024) @ w4^T(512x1024) --------------------------------
__global__ __launch_bounds__(256) void k_fc4(const float* __restrict__ w4, float* W) {
    __shared__ float red[256];
    const int t = threadIdx.x;
    const int oidx = t >> 3, s = t & 7;
    const int cc = oidx >> 3, b = oidx & 7;
    const int c = blockIdx.x * 4 + cc;
    const float* g = &W[OFF_GMAX];
    const float* wr = &w4[c * 1024 + s * 128];
    const float* gr = &g[b * 1024 + s * 128];
    float p = 0.f;
    for (int j = 0; j < 128; ++j) p += wr[j] * gr[j];
    red[t] = p;
    __syncthreads();
    if (t < 32) {
        float tot = 0.f;
        for (int k = 0; k < 8; ++k) tot += red[t * 8 + k];
        W[OFF_Z4 + (t & 7) * 512 + blockIdx.x * 4 + (t >> 3)] = tot;
    }
}

// -------- tail: bn4+relu, fc5, bn5+relu, final linear + eye -----------------
__global__ __launch_bounds__(512) void k_tail(const float* __restrict__ g4, const float* __restrict__ b4,
                                              const float* __restrict__ w5, const float* __restrict__ g5,
                                              const float* __restrict__ b5, const float* __restrict__ wl,
                                              const float* __restrict__ bl, float* W, float* __restrict__ out) {
    __shared__ float h4L[8 * 512];
    __shared__ float w5s[2 * 256 * 9];
    __shared__ float zp[2 * 2048];
    const int t = threadIdx.x;
    {
        float v[8]; float s = 0.f, q = 0.f;
#pragma unroll
        for (int b = 0; b < 8; ++b) { v[b] = W[OFF_Z4 + b * 512 + t]; s += v[b]; q += v[b] * v[b]; }
        float mean = s * 0.125f;
        float var = q * 0.125f - mean * mean;
        float sc = g4[t] * rsqrtf(var + BNEPS);
        float sh = b4[t] - mean * sc;
#pragma unroll
        for (int b = 0; b < 8; ++b) {
            float h = sc * v[b] + sh;
            h4L[b * 512 + t] = h > 0.f ? h : 0.f;
        }
    }
    const int c5 = t & 255, half = t >> 8;
    float acc[8];
#pragma unroll
    for (int b = 0; b < 8; ++b) acc[b] = 0.f;
    for (int jt = 0; jt < 32; ++jt) {
        __syncthreads();
        for (int i = t; i < 4096; i += 512) {
            int h = i >> 11, rem = i & 2047;
            int ci = rem >> 3, jj = rem & 7;
            w5s[h * 2304 + ci * 9 + jj] = w5[ci * 512 + h * 256 + jt * 8 + jj];
        }
        __syncthreads();
#pragma unroll
        for (int jj = 0; jj < 8; ++jj) {
            float wv = w5s[half * 2304 + c5 * 9 + jj];
            int jg = half * 256 + jt * 8 + jj;
#pragma unroll
            for (int b = 0; b < 8; ++b) acc[b] += wv * h4L[b * 512 + jg];
        }
    }
#pragma unroll
    for (int b = 0; b < 8; ++b) zp[half * 2048 + b * 256 + c5] = acc[b];
    __syncthreads();
    if (t < 256) {
        float v[8], s = 0.f, q = 0.f;
#pragma unroll
        for (int b = 0; b < 8; ++b) {
            v[b] = zp[b * 256 + t] + zp[2048 + b * 256 + t];
            s += v[b]; q += v[b] * v[b];
        }
        float mean = s * 0.125f, var = q * 0.125f - mean * mean;
        float sc = g5[t] * rsqrtf(var + BNEPS), sh = b5[t] - mean * sc;
#pragma unroll
        for (int b = 0; b < 8; ++b) { float h = sc * v[b] + sh; zp[b * 256 + t] = h > 0.f ? h : 0.f; }
    }
    __syncthreads();
    if (t < 72) {
        int b = t / 9, r = t % 9;
        float a = bl[r] + ((r == 0 || r == 4 || r == 8) ? 1.f : 0.f);
        for (int j = 0; j < 256; ++j) a += wl[r * 256 + j] * zp[b * 256 + j];
        out[b * 9 + r] = a;
    }
}

extern "C" void kernel_launch(void* const* d_in, const int* in_sizes, int n_in,
                              void* d_out, int out_size, void* d_ws, size_t ws_size,
                              hipStream_t stream) {
    const float* x  = (const float*)d_in[0];
    const float* w1 = (const float*)d_in[1];
    const float* g1 = (const float*)d_in[2];
    const float* b1 = (const float*)d_in[3];
    const float* w2 = (const float*)d_in[4];
    const float* g2 = (const float*)d_in[5];
    const float* b2 = (const float*)d_in[6];
    const float* w3 = (const float*)d_in[7];
    const float* g3 = (const float*)d_in[8];
    const float* b3 = (const float*)d_in[9];
    const float* w4 = (const float*)d_in[10];
    const float* g4 = (const float*)d_in[11];
    const float* b4 = (const float*)d_in[12];
    const float* w5 = (const float*)d_in[13];
    const float* g5 = (const float*)d_in[14];
    const float* b5 = (const float*)d_in[15];
    const float* wl = (const float*)d_in[16];
    const float* bl = (const float*)d_in[17];
    float* W = (float*)d_ws;
    int* idx = (int*)d_ws;
    float* out = (float*)d_out;

    k_init<<<dim3(69), dim3(256), 0, stream>>>(W, ZERO1_BEG, ZERO1_CNT);
    k_knn<<<dim3(1024, 8), dim3(256), 0, stream>>>(x, idx, W);
    k_fin1<<<dim3(1), dim3(64), 0, stream>>>(w1, g1, b1, W);
    k_gram1<<<dim3(512), dim3(256), 0, stream>>>(x, idx, w1, W);
    k_fin2<<<dim3(1), dim3(256), 0, stream>>>(w2, g2, b2, W);
    k_c2apply<<<dim3(1024, 8), dim3(320), 0, stream>>>(x, idx, w1, w2, W);
    k_init<<<dim3(161), dim3(256), 0, stream>>>(W, ZERO2_BEG, ZERO2_CNT);
    k_gram3<<<dim3(64), dim3(256), 0, stream>>>(W);
    k_fin3<<<dim3(64), dim3(256), 0, stream>>>(w3, g3, b3, W);
    k_conv3<<<dim3(512, 16), dim3(256), 0, stream>>>(w3, W);
    k_fc4<<<dim3(128), dim3(256), 0, stream>>>(w4, W);
    k_tail<<<dim3(1), dim3(512), 0, stream>>>(g4, b4, w5, g5, b5, wl, bl, W, out);
}

// Round 5
// 763.772 us; speedup vs baseline: 26.2815x; 1.5253x over previous
//
#include <hip/hip_runtime.h>

#define NPTS 4096
#define KNN 20
#define CNT1f 655360.0f   // B*N*K
#define CNT3f 32768.0f    // B*N
#define BNEPS 1e-5f

// ---- workspace layout (float offsets into d_ws) ----
// Phase aliasing: [idx region 0..655360) holds idx until k_c2apply is done,
// then is reused for G3/SM3/GMAX/Z4. [region at 655360) holds phase-1 stats
// accumulators until fin2, then bf16 M overwrites them (M = 2097152 floats).
#define OFF_IDX   0
#define OFF_G3P   0          // 2*16384   (alias, after c2apply)
#define OFF_SM3P  32768      // 2*128
#define OFF_GMAX  33024      // 8*1024
#define OFF_Z4    41216      // 8*512
#define OFF_M     655360     // bf16[32768*128] = 2097152 floats
#define OFF_ES    655360     // 32 partials x 32 (27 used)  (alias, pre-c2apply)
#define OFF_G1P   656384     // 4*4096
#define OFF_S1P   672768     // 4*64
#define ZERO1_BEG 655360
#define ZERO1_CNT 17664
#define ZERO2_BEG 0
#define ZERO2_CNT 41216
#define OFF_SC1   4849664
#define OFF_SH1   4849728
#define OFF_SC2   4849792
#define OFF_SH2   4849920
#define OFF_SC3   4850048
#define OFF_SH3   4851072

typedef float f32x4 __attribute__((ext_vector_type(4)));
typedef short s16x8 __attribute__((ext_vector_type(8)));

__device__ __forceinline__ unsigned short f2bf(float f) {   // RNE fp32->bf16
    unsigned u = __float_as_uint(f);
    return (unsigned short)((u + 0x7FFFu + ((u >> 16) & 1u)) >> 16);
}

__global__ __launch_bounds__(256) void k_init(float* W, int beg, int cnt) {
    int i = blockIdx.x * 256 + threadIdx.x;
    if (i < cnt) W[beg + i] = 0.0f;
}

// ---- wave-wide: find bin B containing the K-th smallest (1-indexed) in H ----
template <int PER>
__device__ __forceinline__ void wave_scan_find(const int* H, int K, int lane,
                                               int& B, int& below, int& hB) {
    int c[PER]; int s = 0;
    const int base = lane * PER;
#pragma unroll
    for (int p = 0; p < PER; ++p) { c[p] = H[base + p]; s += c[p]; }
    int pre = s;
#pragma unroll
    for (int off = 1; off < 64; off <<= 1) {
        int t = __shfl_up(pre, off, 64);
        if (lane >= off) pre += t;
    }
    int excl = pre - s;
    bool has = (excl < K) && (K <= excl + s);
    unsigned long long m = __ballot(has);
    int src = (int)(__ffsll((unsigned long long)m) - 1);
    int mb = 0, mbelow = 0, mh = 0;
    if (lane == src) {
        int cum = excl;
#pragma unroll
        for (int p = 0; p < PER; ++p) {
            if (cum < K && K <= cum + c[p]) { mb = base + p; mbelow = cum; mh = c[p]; break; }
            cum += c[p];
        }
    }
    B = __shfl(mb, src, 64);
    below = __shfl(mbelow, src, 64);
    hB = __shfl(mh, src, 64);
}

// -------- KNN via radix-select: 1 wave/query, keys cached in VGPRs ----------
__global__ __launch_bounds__(256) void k_knn(const float* __restrict__ x, int* __restrict__ idx, float* W) {
    __shared__ float px[NPTS], py[NPTS], pz[NPTS];   // 48 KB
    __shared__ int hist[4][256];                     // 4 KB
    __shared__ int outi[4][20];
    __shared__ int cnts[4][2];
    __shared__ float estat[27];
    const int tid = threadIdx.x;
    const int b = blockIdx.y;
    const float* xb = x + b * 3 * NPTS;
    for (int i = tid; i < NPTS; i += 256) {
        px[i] = xb[i]; py[i] = xb[NPTS + i]; pz[i] = xb[2 * NPTS + i];
    }
    if (tid < 27) estat[tid] = 0.f;
    if (tid < 8) cnts[tid >> 1][tid & 1] = 0;
    __syncthreads();
    const int wv = tid >> 6, lane = tid & 63;
    const int q = blockIdx.x * 4 + wv;
    const float qx = px[q], qy = py[q], qz = pz[q];
    int* H = hist[wv];
    unsigned int key[64];
#pragma unroll
    for (int p = 0; p < 4; ++p) H[lane * 4 + p] = 0;
#pragma unroll
    for (int it = 0; it < 64; ++it) {
        int j = it * 64 + lane;
        float dx = px[j] - qx, dy = py[j] - qy, dz = pz[j] - qz;
        float d = fmaf(dx, dx, fmaf(dy, dy, dz * dz));
        unsigned int u = __float_as_uint(d);
        key[it] = u;
        atomicAdd(&H[u >> 23], 1);
    }
    int B, below, hB;
    wave_scan_find<4>(H, KNN, lane, B, below, hB);
    unsigned int P = (unsigned int)B;
    int rem = KNN - below;
    int S = 23;
    if (hB != rem) {
#pragma unroll
        for (int p = 0; p < 4; ++p) H[lane * 4 + p] = 0;
#pragma unroll
        for (int it = 0; it < 64; ++it) {
            unsigned int u = key[it];
            if ((u >> 23) == P) atomicAdd(&H[(u >> 15) & 255], 1);
        }
        wave_scan_find<4>(H, rem, lane, B, below, hB);
        P = (P << 8) | (unsigned int)B;
        rem -= below;
        S = 15;
        if (hB != rem) {
#pragma unroll
            for (int p = 0; p < 4; ++p) H[lane * 4 + p] = 0;
#pragma unroll
            for (int it = 0; it < 64; ++it) {
                unsigned int u = key[it];
                if ((u >> 15) == P) atomicAdd(&H[(u >> 7) & 255], 1);
            }
            wave_scan_find<4>(H, rem, lane, B, below, hB);
            P = (P << 8) | (unsigned int)B;
            rem -= below;
            S = 7;
        }
    }
    int* OC = cnts[wv];
#pragma unroll
    for (int it = 0; it < 64; ++it) {
        unsigned int k = key[it] >> S;
        if (k <= P) {
            bool take = true;
            if (k == P) { int e = atomicAdd(&OC[1], 1); take = (e < rem); }
            if (take) { int pos = atomicAdd(&OC[0], 1); outi[wv][pos] = it * 64 + lane; }
        }
    }
    const int obase = (b * NPTS + q) * KNN;
    if (lane < KNN) idx[obase + lane] = outi[wv][lane];
    // fused edge moments for bn1
    float st[27];
#pragma unroll
    for (int v = 0; v < 27; ++v) st[v] = 0.f;
    if (lane < KNN) {
        int j = outi[wv][lane];
        float e[6];
        e[0] = qx; e[1] = qy; e[2] = qz;
        e[3] = px[j] - qx; e[4] = py[j] - qy; e[5] = pz[j] - qz;
        int id = 6;
#pragma unroll
        for (int i = 0; i < 6; ++i) {
            st[i] = e[i];
#pragma unroll
            for (int jj = i; jj < 6; ++jj) { st[id] = e[i] * e[jj]; id++; }
        }
    }
#pragma unroll
    for (int v = 0; v < 27; ++v) {
        float s = st[v];
        s += __shfl_xor(s, 32); s += __shfl_xor(s, 16); s += __shfl_xor(s, 8);
        s += __shfl_xor(s, 4);  s += __shfl_xor(s, 2);  s += __shfl_xor(s, 1);
        st[v] = s;
    }
    if (lane == 0) {
#pragma unroll
        for (int v = 0; v < 27; ++v) atomicAdd(&estat[v], st[v]);
    }
    __syncthreads();
    if (tid < 27) atomicAdd(&W[OFF_ES + (blockIdx.x & 31) * 32 + tid], estat[tid]);
}

// bn1 affine from edge moments
__global__ void k_fin1(const float* __restrict__ w1, const float* __restrict__ g1,
                       const float* __restrict__ b1, float* W) {
    __shared__ float es[27];
    const int c = threadIdx.x;
    if (c < 27) {
        float s = 0.f;
        for (int p = 0; p < 32; ++p) s += W[OFF_ES + p * 32 + c];
        es[c] = s;
    }
    __syncthreads();
    float wr[6];
#pragma unroll
    for (int i = 0; i < 6; ++i) wr[i] = w1[c * 6 + i];
    float m = 0.f;
#pragma unroll
    for (int i = 0; i < 6; ++i) m += wr[i] * es[i];
    m *= (1.f / CNT1f);
    float qv = 0.f;
    int id = 6;
#pragma unroll
    for (int i = 0; i < 6; ++i)
#pragma unroll
        for (int jj = 0; jj < 6; ++jj)
            if (jj >= i) { qv += (jj == i ? 1.f : 2.f) * wr[i] * wr[jj] * es[id]; id++; }
    qv *= (1.f / CNT1f);
    float var = qv - m * m;
    float sc = g1[c] * rsqrtf(var + BNEPS);
    W[OFF_SC1 + c] = sc;
    W[OFF_SH1 + c] = b1[c] - m * sc;
}

// -------- gram1 (MFMA): G1 = Sum(h1 h1^T), S1 via appended ones-row ---------
// h1t layout [row][edge] bf16, rows 0..63 = chans, row 64 = ones, 65..79 = 0.
// Same buffer serves A and B fragments of the 16x16x32 bf16 MFMA.
__global__ __launch_bounds__(256) void k_gram1(const float* __restrict__ x, const int* __restrict__ idx,
                                               const float* __restrict__ w1, float* W) {
    __shared__ unsigned short h1t[80 * 136];   // 21760 B
    __shared__ float eds[128 * 6];
    __shared__ float w1s[64 * 6];
    __shared__ float sc1s[64], sh1s[64];
    const int t = threadIdx.x;
    const int b = blockIdx.x >> 6;                 // 64 blocks per batch
    const int ebase_b = (blockIdx.x & 63) * 1280;  // edges within batch
    const float* xb = x + b * 3 * NPTS;
    if (t < 384) w1s[t] = w1[t];
    if (t < 64) { sc1s[t] = W[OFF_SC1 + t]; sh1s[t] = W[OFF_SH1 + t]; }
    for (int i = t; i < 2048; i += 256) {          // rows 64..79
        int rr = i >> 7, e = i & 127;
        h1t[(64 + rr) * 136 + e] = (rr == 0) ? (unsigned short)0x3F80 : (unsigned short)0;
    }
    const int w = t >> 6, lane = t & 63, n16 = lane & 15, quad = lane >> 4;
    f32x4 acc[5];
#pragma unroll
    for (int j = 0; j < 5; ++j) acc[j] = (f32x4){0.f, 0.f, 0.f, 0.f};
    for (int ck = 0; ck < 10; ++ck) {
        __syncthreads();
        if (t < 128) {   // stage 128 edges
            int e_l = ebase_b + ck * 128 + t;
            int q = e_l / KNN;
            int jn = idx[b * (NPTS * KNN) + e_l];
            float cx = xb[q], cy = xb[NPTS + q], cz = xb[2 * NPTS + q];
            float* E = &eds[t * 6];
            E[0] = cx; E[1] = cy; E[2] = cz;
            E[3] = xb[jn] - cx; E[4] = xb[NPTS + jn] - cy; E[5] = xb[2 * NPTS + jn] - cz;
        }
        __syncthreads();
        {   // h1 rows 0..63: thread = (edge, half of chans); w1s reads broadcast
            const int e128 = t & 127, half = t >> 7;
            float e0 = eds[e128 * 6 + 0], e1 = eds[e128 * 6 + 1], e2 = eds[e128 * 6 + 2];
            float e3 = eds[e128 * 6 + 3], e4 = eds[e128 * 6 + 4], e5 = eds[e128 * 6 + 5];
#pragma unroll 4
            for (int cc = 0; cc < 32; ++cc) {
                int c = half * 32 + cc;
                const float* wr = &w1s[c * 6];
                float z = wr[0] * e0 + wr[1] * e1 + wr[2] * e2 + wr[3] * e3 + wr[4] * e4 + wr[5] * e5;
                float h = sc1s[c] * z + sh1s[c];
                h1t[c * 136 + e128] = f2bf(h > 0.f ? h : 0.f);
            }
        }
        __syncthreads();
#pragma unroll
        for (int ks = 0; ks < 4; ++ks) {
            s16x8 Af = *(const s16x8*)&h1t[(w * 16 + n16) * 136 + ks * 32 + quad * 8];
#pragma unroll
            for (int jt = 0; jt < 5; ++jt) {
                s16x8 Bf = *(const s16x8*)&h1t[(jt * 16 + n16) * 136 + ks * 32 + quad * 8];
                acc[jt] = __builtin_amdgcn_mfma_f32_16x16x32_bf16(Af, Bf, acc[jt], 0, 0, 0);
            }
        }
    }
    const int part = blockIdx.x & 3;
    const int gi = w * 16 + quad * 4;
#pragma unroll
    for (int jt = 0; jt < 4; ++jt)
#pragma unroll
        for (int r = 0; r < 4; ++r)
            atomicAdd(&W[OFF_G1P + part * 4096 + (gi + r) * 64 + jt * 16 + n16], acc[jt][r]);
    if (n16 == 0) {
#pragma unroll
        for (int r = 0; r < 4; ++r)
            atomicAdd(&W[OFF_S1P + part * 64 + gi + r], acc[4][r]);
    }
}

// bn2 affine from Gram
__global__ __launch_bounds__(256) void k_fin2(const float* __restrict__ w2, const float* __restrict__ g2,
                                              const float* __restrict__ b2, float* W) {
    __shared__ float Gs[4096];
    __shared__ float s1s[64];
    __shared__ float w2s[128 * 65];
    const int t = threadIdx.x;
    for (int i = t; i < 4096; i += 256)
        Gs[i] = W[OFF_G1P + i] + W[OFF_G1P + 4096 + i] + W[OFF_G1P + 8192 + i] + W[OFF_G1P + 12288 + i];
    if (t < 64) s1s[t] = W[OFF_S1P + t] + W[OFF_S1P + 64 + t] + W[OFF_S1P + 128 + t] + W[OFF_S1P + 192 + t];
    for (int i = t; i < 8192; i += 256) w2s[(i >> 6) * 65 + (i & 63)] = w2[i];
    __syncthreads();
    const int c = t >> 1, half = t & 1;
    float acc = 0.f;
    for (int ii = 0; ii < 32; ++ii) {
        int i = 32 * half + ii;
        float wi = w2s[c * 65 + i];
        float inner = 0.f;
        for (int j = 0; j < 64; ++j) inner += Gs[i * 64 + j] * w2s[c * 65 + j];
        acc += wi * inner;
    }
    acc += __shfl_xor(acc, 1);
    if (half == 0) {
        float ms = 0.f;
        for (int j = 0; j < 64; ++j) ms += w2s[c * 65 + j] * s1s[j];
        float mean = ms * (1.f / CNT1f);
        float var = acc * (1.f / CNT1f) - mean * mean;
        float sc = g2[c] * rsqrtf(var + BNEPS);
        W[OFF_SC2 + c] = sc;
        W[OFF_SH2 + c] = b2[c] - mean * sc;
    }
}

// -------- c2apply (MFMA): conv1+bn1+relu -> conv2 (bf16 MFMA) -> bn2+relu
// -> max over K -> M (bf16). 4 queries/block, rows padded to 32 per query.
__global__ __launch_bounds__(256) void k_c2apply(const float* __restrict__ x, const int* __restrict__ idx,
                                                 const float* __restrict__ w1, const float* __restrict__ w2,
                                                 float* W) {
    __shared__ unsigned short h1b[128 * 72];   // [row=q*32+kk][k=64 chans of h1]
    __shared__ unsigned short w2b[128 * 72];   // [chan(128)][k=64]
    __shared__ float eds[80 * 6];
    const int t = threadIdx.x;
    const int b = blockIdx.y, q0 = blockIdx.x * 4;
    const float* xb = x + b * 3 * NPTS;
    const int ebase = (b * NPTS + q0) * KNN;
    for (int i = t; i < 8192; i += 256) w2b[(i >> 6) * 72 + (i & 63)] = f2bf(w2[i]);
    if (t < 80) {
        int q = q0 + t / KNN;
        int jn = idx[ebase + t];
        float cx = xb[q], cy = xb[NPTS + q], cz = xb[2 * NPTS + q];
        float* E = &eds[t * 6];
        E[0] = cx; E[1] = cy; E[2] = cz;
        E[3] = xb[jn] - cx; E[4] = xb[NPTS + jn] - cy; E[5] = xb[2 * NPTS + jn] - cz;
    }
    __syncthreads();
    {   // h1: thread (chan j64, query grp); pad rows 20..31 with zeros
        const int j64 = t & 63, grp = t >> 6;
        float wr[6];
#pragma unroll
        for (int i = 0; i < 6; ++i) wr[i] = w1[j64 * 6 + i];
        const float sc = W[OFF_SC1 + j64], sh = W[OFF_SH1 + j64];
#pragma unroll 4
        for (int kk = 0; kk < 32; ++kk) {
            float v = 0.f;
            if (kk < 20) {
                const float* E = &eds[(grp * 20 + kk) * 6];
                float z = wr[0] * E[0] + wr[1] * E[1] + wr[2] * E[2] + wr[3] * E[3] + wr[4] * E[4] + wr[5] * E[5];
                float h = sc * z + sh;
                v = h > 0.f ? h : 0.f;
            }
            h1b[(grp * 32 + kk) * 72 + j64] = f2bf(v);
        }
    }
    __syncthreads();
    const int w = t >> 6, lane = t & 63, n16 = lane & 15, quad = lane >> 4;
    unsigned short* Mb = (unsigned short*)(W + OFF_M);
#pragma unroll
    for (int nt_i = 0; nt_i < 2; ++nt_i) {
        const int nt = 2 * w + nt_i;
        const int chan = nt * 16 + n16;
        const float sc2 = W[OFF_SC2 + chan], sh2 = W[OFF_SH2 + chan];
        s16x8 Bf0 = *(const s16x8*)&w2b[chan * 72 + quad * 8];
        s16x8 Bf1 = *(const s16x8*)&w2b[chan * 72 + 32 + quad * 8];
#pragma unroll
        for (int q = 0; q < 4; ++q) {
            f32x4 accA = (f32x4){0.f, 0.f, 0.f, 0.f};
            f32x4 accB = (f32x4){0.f, 0.f, 0.f, 0.f};
            s16x8 a0 = *(const s16x8*)&h1b[(q * 32 + n16) * 72 + quad * 8];
            s16x8 a1 = *(const s16x8*)&h1b[(q * 32 + 16 + n16) * 72 + quad * 8];
            accA = __builtin_amdgcn_mfma_f32_16x16x32_bf16(a0, Bf0, accA, 0, 0, 0);
            accB = __builtin_amdgcn_mfma_f32_16x16x32_bf16(a1, Bf0, accB, 0, 0, 0);
            a0 = *(const s16x8*)&h1b[(q * 32 + n16) * 72 + 32 + quad * 8];
            a1 = *(const s16x8*)&h1b[(q * 32 + 16 + n16) * 72 + 32 + quad * 8];
            accA = __builtin_amdgcn_mfma_f32_16x16x32_bf16(a0, Bf1, accA, 0, 0, 0);
            accB = __builtin_amdgcn_mfma_f32_16x16x32_bf16(a1, Bf1, accB, 0, 0, 0);
            // epilogue: rows of accA = kk 0..15 (valid); accB rows = 16+quad*4+r
            float mx = 0.f;
#pragma unroll
            for (int r = 0; r < 4; ++r) {
                float h = sc2 * accA[r] + sh2;
                mx = fmaxf(mx, h > 0.f ? h : 0.f);
            }
            if (quad == 0) {   // kk = 16..19 valid only in quad 0
#pragma unroll
                for (int r = 0; r < 4; ++r) {
                    float h = sc2 * accB[r] + sh2;
                    mx = fmaxf(mx, h > 0.f ? h : 0.f);
                }
            }
            mx = fmaxf(mx, __shfl_xor(mx, 16));
            mx = fmaxf(mx, __shfl_xor(mx, 32));
            if (quad == 0)
                Mb[(b * NPTS + q0 + q) * 128 + chan] = f2bf(mx);
        }
    }
}

// -------- G3 = M^T M (128x128) and Sum(m) for bn3 (M is bf16) ---------------
__global__ __launch_bounds__(256) void k_gram3(float* W) {
    __shared__ float Ms[64 * 132];
    const int t = threadIdx.x;
    const int rg = t & 15, cg = t >> 4;
    const int r0 = blockIdx.x * 512;
    const unsigned int* Msrc = (const unsigned int*)(W + OFF_M);
    float acc[8][8];
#pragma unroll
    for (int i = 0; i < 8; ++i)
#pragma unroll
        for (int j = 0; j < 8; ++j) acc[i][j] = 0.f;
    float smacc = 0.f;
    for (int ch = 0; ch < 8; ++ch) {
        __syncthreads();
        for (int i = t; i < 4096; i += 256) {
            unsigned int v = Msrc[(r0 + ch * 64) * 64 + i];
            int row = i >> 6, c2 = i & 63;
            Ms[row * 132 + 2 * c2]     = __uint_as_float(v << 16);
            Ms[row * 132 + 2 * c2 + 1] = __uint_as_float(v & 0xFFFF0000u);
        }
        __syncthreads();
#pragma unroll 2
        for (int e = 0; e < 64; ++e) {
            float4 x0 = *(const float4*)&Ms[e * 132 + 8 * rg];
            float4 x1 = *(const float4*)&Ms[e * 132 + 8 * rg + 4];
            float4 y0 = *(const float4*)&Ms[e * 132 + 8 * cg];
            float4 y1 = *(const float4*)&Ms[e * 132 + 8 * cg + 4];
            float av[8] = {x0.x, x0.y, x0.z, x0.w, x1.x, x1.y, x1.z, x1.w};
            float bv[8] = {y0.x, y0.y, y0.z, y0.w, y1.x, y1.y, y1.z, y1.w};
#pragma unroll
            for (int i = 0; i < 8; ++i)
#pragma unroll
                for (int j = 0; j < 8; ++j) acc[i][j] += av[i] * bv[j];
        }
        if (t < 128) {
            float s = 0.f;
            for (int e = 0; e < 64; ++e) s += Ms[e * 132 + t];
            smacc += s;
        }
    }
    const int part = blockIdx.x & 1;
    float* Gp = &W[OFF_G3P + part * 16384];
#pragma unroll
    for (int i = 0; i < 8; ++i)
#pragma unroll
        for (int j = 0; j < 8; ++j)
            atomicAdd(&Gp[(8 * rg + i) * 128 + 8 * cg + j], acc[i][j]);
    if (t < 128) atomicAdd(&W[OFF_SM3P + part * 128 + t], smacc);
}

// bn3 affine: 16 channels per block
__global__ __launch_bounds__(256) void k_fin3(const float* __restrict__ w3, const float* __restrict__ g3,
                                              const float* __restrict__ b3, float* W) {
    __shared__ float G3s[128 * 129];
    __shared__ float w3s[16 * 132];
    __shared__ float sm3[128];
    __shared__ float red[256];
    __shared__ float mred[16];
    const int t = threadIdx.x;
    const int c0 = blockIdx.x * 16;
    for (int i = t; i < 16384; i += 256)
        G3s[(i >> 7) * 129 + (i & 127)] = W[OFF_G3P + i] + W[OFF_G3P + 16384 + i];
    for (int i = t; i < 2048; i += 256)
        w3s[(i >> 7) * 132 + (i & 127)] = w3[(c0 + (i >> 7)) * 128 + (i & 127)];
    if (t < 128) sm3[t] = W[OFF_SM3P + t] + W[OFF_SM3P + 128 + t];
    __syncthreads();
    const int cl = t >> 4, seg = t & 15;
    float acc = 0.f;
    for (int ii = 0; ii < 8; ++ii) {
        int i = 8 * seg + ii;
        float wi = w3s[cl * 132 + i];
        float inner = 0.f;
        for (int j = 0; j < 128; ++j) inner += G3s[i * 129 + j] * w3s[cl * 132 + j];
        acc += wi * inner;
    }
    red[t] = acc;
    if (seg == 0) {
        float ms = 0.f;
        for (int j = 0; j < 128; ++j) ms += w3s[cl * 132 + j] * sm3[j];
        mred[cl] = ms;
    }
    __syncthreads();
    if (t < 16) {
        float s = 0.f;
#pragma unroll
        for (int k = 0; k < 16; ++k) s += red[t * 16 + k];
        float mean = mred[t] * (1.f / CNT3f);
        float var = s * (1.f / CNT3f) - mean * mean;
        float sc = g3[c0 + t] * rsqrtf(var + BNEPS);
        W[OFF_SC3 + c0 + t] = sc;
        W[OFF_SH3 + c0 + t] = b3[c0 + t] - mean * sc;
    }
}

// -------- conv3 (MFMA): z3 = M @ w3^T, bn3+relu, max over rows -> GMAX ------
__global__ __launch_bounds__(256) void k_conv3(const float* __restrict__ w3, float* W) {
    __shared__ unsigned short Mt[64 * 136];     // 64 rows x K=128
    __shared__ unsigned short w3b[128 * 136];   // 128 chans x K=128
    const int t = threadIdx.x;
    const int p0 = blockIdx.x * 64, c0g = blockIdx.y * 128;
    const unsigned int* Msrc = (const unsigned int*)(W + OFF_M);
    for (int i = t; i < 4096; i += 256) {
        int row = i >> 6, c2 = i & 63;
        *(unsigned int*)&Mt[row * 136 + 2 * c2] = Msrc[(p0 + row) * 64 + c2];
    }
    for (int i = t; i < 16384; i += 256) {
        int c = i >> 7, k = i & 127;
        w3b[c * 136 + k] = f2bf(w3[(c0g + c) * 128 + k]);
    }
    __syncthreads();
    const int w = t >> 6, lane = t & 63, n16 = lane & 15, quad = lane >> 4;
    const int bbatch = p0 >> 12;
#pragma unroll
    for (int nt_i = 0; nt_i < 2; ++nt_i) {
        const int nt = 2 * w + nt_i;
        const int chan_l = nt * 16 + n16;
        const int chan = c0g + chan_l;
        const float sc3 = W[OFF_SC3 + chan], sh3 = W[OFF_SH3 + chan];
        s16x8 Bf[4];
#pragma unroll
        for (int ks = 0; ks < 4; ++ks)
            Bf[ks] = *(const s16x8*)&w3b[chan_l * 136 + ks * 32 + quad * 8];
        float mx = 0.f;
#pragma unroll
        for (int mt = 0; mt < 4; ++mt) {
            f32x4 acc = (f32x4){0.f, 0.f, 0.f, 0.f};
#pragma unroll
            for (int ks = 0; ks < 4; ++ks) {
                s16x8 Af = *(const s16x8*)&Mt[(mt * 16 + n16) * 136 + ks * 32 + quad * 8];
                acc = __builtin_amdgcn_mfma_f32_16x16x32_bf16(Af, Bf[ks], acc, 0, 0, 0);
            }
#pragma unroll
            for (int r = 0; r < 4; ++r) {
                float h = sc3 * acc[r] + sh3;
                mx = fmaxf(mx, h > 0.f ? h : 0.f);
            }
        }
        mx = fmaxf(mx, __shfl_xor(mx, 16));
        mx = fmaxf(mx, __shfl_xor(mx, 32));
        if (quad == 0)
            atomicMax((unsigned int*)&W[OFF_GMAX + bbatch * 1024 + chan], __float_as_uint(mx));
    }
}

// -------- z4 = gmax(8x1024) @ w4^T(512x1024) --------------------------------
__global__ __launch_bounds__(256) void k_fc4(const float* __restrict__ w4, float* W) {
    __shared__ float red[256];
    const int t = threadIdx.x;
    const int oidx = t >> 3, s = t & 7;
    const int cc = oidx >> 3, b = oidx & 7;
    const int c = blockIdx.x * 4 + cc;
    const float* g = &W[OFF_GMAX];
    const float* wr = &w4[c * 1024 + s * 128];
    const float* gr = &g[b * 1024 + s * 128];
    float p = 0.f;
    for (int j = 0; j < 128; ++j) p += wr[j] * gr[j];
    red[t] = p;
    __syncthreads();
    if (t < 32) {
        float tot = 0.f;
        for (int k = 0; k < 8; ++k) tot += red[t * 8 + k];
        W[OFF_Z4 + (t & 7) * 512 + blockIdx.x * 4 + (t >> 3)] = tot;
    }
}

// -------- tail: bn4+relu, fc5, bn5+relu, final linear + eye -----------------
__global__ __launch_bounds__(512) void k_tail(const float* __restrict__ g4, const float* __restrict__ b4,
                                              const float* __restrict__ w5, const float* __restrict__ g5,
                                              const float* __restrict__ b5, const float* __restrict__ wl,
                                              const float* __restrict__ bl, float* W, float* __restrict__ out) {
    __shared__ float h4L[8 * 512];
    __shared__ float w5s[2 * 256 * 9];
    __shared__ float zp[2 * 2048];
    const int t = threadIdx.x;
    {
        float v[8]; float s = 0.f, q = 0.f;
#pragma unroll
        for (int b = 0; b < 8; ++b) { v[b] = W[OFF_Z4 + b * 512 + t]; s += v[b]; q += v[b] * v[b]; }
        float mean = s * 0.125f;
        float var = q * 0.125f - mean * mean;
        float sc = g4[t] * rsqrtf(var + BNEPS);
        float sh = b4[t] - mean * sc;
#pragma unroll
        for (int b = 0; b < 8; ++b) {
            float h = sc * v[b] + sh;
            h4L[b * 512 + t] = h > 0.f ? h : 0.f;
        }
    }
    const int c5 = t & 255, half = t >> 8;
    float acc[8];
#pragma unroll
    for (int b = 0; b < 8; ++b) acc[b] = 0.f;
    for (int jt = 0; jt < 32; ++jt) {
        __syncthreads();
        for (int i = t; i < 4096; i += 512) {
            int h = i >> 11, rem = i & 2047;
            int ci = rem >> 3, jj = rem & 7;
            w5s[h * 2304 + ci * 9 + jj] = w5[ci * 512 + h * 256 + jt * 8 + jj];
        }
        __syncthreads();
#pragma unroll
        for (int jj = 0; jj < 8; ++jj) {
            float wv = w5s[half * 2304 + c5 * 9 + jj];
            int jg = half * 256 + jt * 8 + jj;
#pragma unroll
            for (int b = 0; b < 8; ++b) acc[b] += wv * h4L[b * 512 + jg];
        }
    }
#pragma unroll
    for (int b = 0; b < 8; ++b) zp[half * 2048 + b * 256 + c5] = acc[b];
    __syncthreads();
    if (t < 256) {
        float v[8], s = 0.f, q = 0.f;
#pragma unroll
        for (int b = 0; b < 8; ++b) {
            v[b] = zp[b * 256 + t] + zp[2048 + b * 256 + t];
            s += v[b]; q += v[b] * v[b];
        }
        float mean = s * 0.125f, var = q * 0.125f - mean * mean;
        float sc = g5[t] * rsqrtf(var + BNEPS), sh = b5[t] - mean * sc;
#pragma unroll
        for (int b = 0; b < 8; ++b) { float h = sc * v[b] + sh; zp[b * 256 + t] = h > 0.f ? h : 0.f; }
    }
    __syncthreads();
    if (t < 72) {
        int b = t / 9, r = t % 9;
        float a = bl[r] + ((r == 0 || r == 4 || r == 8) ? 1.f : 0.f);
        for (int j = 0; j < 256; ++j) a += wl[r * 256 + j] * zp[b * 256 + j];
        out[b * 9 + r] = a;
    }
}

extern "C" void kernel_launch(void* const* d_in, const int* in_sizes, int n_in,
                              void* d_out, int out_size, void* d_ws, size_t ws_size,
                              hipStream_t stream) {
    const float* x  = (const float*)d_in[0];
    const float* w1 = (const float*)d_in[1];
    const float* g1 = (const float*)d_in[2];
    const float* b1 = (const float*)d_in[3];
    const float* w2 = (const float*)d_in[4];
    const float* g2 = (const float*)d_in[5];
    const float* b2 = (const float*)d_in[6];
    const float* w3 = (const float*)d_in[7];
    const float* g3 = (const float*)d_in[8];
    const float* b3 = (const float*)d_in[9];
    const float* w4 = (const float*)d_in[10];
    const float* g4 = (const float*)d_in[11];
    const float* b4 = (const float*)d_in[12];
    const float* w5 = (const float*)d_in[13];
    const float* g5 = (const float*)d_in[14];
    const float* b5 = (const float*)d_in[15];
    const float* wl = (const float*)d_in[16];
    const float* bl = (const float*)d_in[17];
    float* W = (float*)d_ws;
    int* idx = (int*)d_ws;
    float* out = (float*)d_out;

    k_init<<<dim3(69), dim3(256), 0, stream>>>(W, ZERO1_BEG, ZERO1_CNT);
    k_knn<<<dim3(1024, 8), dim3(256), 0, stream>>>(x, idx, W);
    k_fin1<<<dim3(1), dim3(64), 0, stream>>>(w1, g1, b1, W);
    k_gram1<<<dim3(512), dim3(256), 0, stream>>>(x, idx, w1, W);
    k_fin2<<<dim3(1), dim3(256), 0, stream>>>(w2, g2, b2, W);
    k_c2apply<<<dim3(1024, 8), dim3(256), 0, stream>>>(x, idx, w1, w2, W);
    k_init<<<dim3(161), dim3(256), 0, stream>>>(W, ZERO2_BEG, ZERO2_CNT);
    k_gram3<<<dim3(64), dim3(256), 0, stream>>>(W);
    k_fin3<<<dim3(64), dim3(256), 0, stream>>>(w3, g3, b3, W);
    k_conv3<<<dim3(512, 8), dim3(256), 0, stream>>>(w3, W);
    k_fc4<<<dim3(128), dim3(256), 0, stream>>>(w4, W);
    k_tail<<<dim3(1), dim3(512), 0, stream>>>(g4, b4, w5, g5, b5, wl, bl, W, out);
}

// Round 6
// 689.577 us; speedup vs baseline: 29.1093x; 1.1076x over previous
//
#include <hip/hip_runtime.h>

#define NPTS 4096
#define KNN 20
#define CNT1f 655360.0f   // B*N*K
#define CNT3f 32768.0f    // B*N
#define BNEPS 1e-5f

// ---- workspace layout (float offsets into d_ws) ----
// Phase aliasing: [idx region 0..655360) holds idx until k_c2apply is done,
// then is reused for G3/SM3/GMAX/Z4. [region at 655360) holds phase-1 stats
// accumulators until fin2, then bf16 M overwrites them. Pre-converted bf16
// weights live at 2752512+ (right after M's end), untouched by any phase.
#define OFF_IDX   0
#define OFF_G3P   0          // 2*16384   (alias, after c2apply)
#define OFF_SM3P  32768      // 2*128
#define OFF_GMAX  33024      // 8*1024
#define OFF_Z4    41216      // 8*512
#define OFF_M     655360     // bf16[32768*128] = 2097152 floats -> ends 2752512
#define OFF_ES    655360     // 32 partials x 32 (27 used)  (alias, pre-c2apply)
#define OFF_G1P   656384     // 4*4096
#define OFF_S1P   672768     // 4*64
#define OFF_W2B   2752512    // bf16[8192]   = 4096 floats
#define OFF_W3B   2756608    // bf16[131072] = 65536 floats -> ends 2822144
#define ZERO1_BEG 655360
#define ZERO1_CNT 17664
#define ZERO2_BEG 0
#define ZERO2_CNT 41216
#define OFF_SC1   4849664
#define OFF_SH1   4849728
#define OFF_SC2   4849792
#define OFF_SH2   4849920
#define OFF_SC3   4850048
#define OFF_SH3   4851072

typedef float f32x4 __attribute__((ext_vector_type(4)));
typedef short s16x8 __attribute__((ext_vector_type(8)));

__device__ __forceinline__ unsigned short f2bf(float f) {   // RNE fp32->bf16
    unsigned u = __float_as_uint(f);
    return (unsigned short)((u + 0x7FFFu + ((u >> 16) & 1u)) >> 16);
}

__global__ __launch_bounds__(256) void k_init(float* W, int beg, int cnt) {
    int i = blockIdx.x * 256 + threadIdx.x;
    if (i < cnt) W[beg + i] = 0.0f;
}

// pre-convert w2/w3 to bf16 once (blocks re-read them L2-cached)
__global__ __launch_bounds__(256) void k_prep(const float* __restrict__ w2, const float* __restrict__ w3,
                                              float* W) {
    int i = blockIdx.x * 256 + threadIdx.x;   // grid 512*256 = 131072
    unsigned short* w2b = (unsigned short*)(W + OFF_W2B);
    unsigned short* w3b = (unsigned short*)(W + OFF_W3B);
    if (i < 8192) w2b[i] = f2bf(w2[i]);
    w3b[i] = f2bf(w3[i]);
}

// ---- wave-wide: find bin B containing the K-th smallest (1-indexed) in H ----
template <int PER>
__device__ __forceinline__ void wave_scan_find(const int* H, int K, int lane,
                                               int& B, int& below, int& hB) {
    int c[PER]; int s = 0;
    const int base = lane * PER;
#pragma unroll
    for (int p = 0; p < PER; ++p) { c[p] = H[base + p]; s += c[p]; }
    int pre = s;
#pragma unroll
    for (int off = 1; off < 64; off <<= 1) {
        int t = __shfl_up(pre, off, 64);
        if (lane >= off) pre += t;
    }
    int excl = pre - s;
    bool has = (excl < K) && (K <= excl + s);
    unsigned long long m = __ballot(has);
    int src = (int)(__ffsll((unsigned long long)m) - 1);
    int mb = 0, mbelow = 0, mh = 0;
    if (lane == src) {
        int cum = excl;
#pragma unroll
        for (int p = 0; p < PER; ++p) {
            if (cum < K && K <= cum + c[p]) { mb = base + p; mbelow = cum; mh = c[p]; break; }
            cum += c[p];
        }
    }
    B = __shfl(mb, src, 64);
    below = __shfl(mbelow, src, 64);
    hB = __shfl(mh, src, 64);
}

// -------- KNN via base-offset radix-select: 1 wave/query --------------------
// Keys cached in VGPRs. Self (d=0) excluded from selection, force-appended.
// Bin on (key - waveMin) >> 19 into 1024 bins: 4 extra resolution bits near
// the minimum de-cluster the histogram atomics (conflict fix) and make the
// boundary bin tiny -> usually single-pass. Downstream is order-invariant.
__global__ __launch_bounds__(256) void k_knn(const float* __restrict__ x, int* __restrict__ idx, float* W) {
    __shared__ float px[NPTS], py[NPTS], pz[NPTS];   // 48 KB
    __shared__ int hist[4][1024];                    // 16 KB
    __shared__ int outi[4][20];
    __shared__ int cnts[4][2];
    __shared__ float estat[27];
    const int tid = threadIdx.x;
    const int b = blockIdx.y;
    const float* xb = x + b * 3 * NPTS;
    for (int i = tid; i < NPTS; i += 256) {
        px[i] = xb[i]; py[i] = xb[NPTS + i]; pz[i] = xb[2 * NPTS + i];
    }
    if (tid < 27) estat[tid] = 0.f;
    if (tid < 8) cnts[tid >> 1][tid & 1] = 0;
    __syncthreads();
    const int wv = tid >> 6, lane = tid & 63;
    const int q = blockIdx.x * 4 + wv;
    const float qx = px[q], qy = py[q], qz = pz[q];
    int* H = hist[wv];
    unsigned int key[64];
    unsigned int mymin = 0xFFFFFFFFu;
#pragma unroll
    for (int p = 0; p < 16; ++p) H[lane * 16 + p] = 0;
#pragma unroll
    for (int it = 0; it < 64; ++it) {
        int j = it * 64 + lane;
        float dx = px[j] - qx, dy = py[j] - qy, dz = pz[j] - qz;
        float d = fmaf(dx, dx, fmaf(dy, dy, dz * dz));
        unsigned int u = (j == q) ? 0xFFFFFFFFu : __float_as_uint(d);
        key[it] = u;
        mymin = mymin < u ? mymin : u;
    }
#pragma unroll
    for (int off = 32; off; off >>= 1) {
        unsigned int o = (unsigned int)__shfl_xor((int)mymin, off);
        mymin = mymin < o ? mymin : o;
    }
    const unsigned int base = mymin;
#pragma unroll
    for (int it = 0; it < 64; ++it) {
        unsigned int t9 = key[it] - base;
        unsigned int bin = t9 >> 19; if (bin > 1023u) bin = 1023u;
        atomicAdd(&H[bin], 1);
    }
    int B, below, hB;
    wave_scan_find<16>(H, KNN - 1, lane, B, below, hB);
    unsigned int P = (unsigned int)B;
    int rem = (KNN - 1) - below;
    int S = 19;
    if (hB != rem) {
#pragma unroll
        for (int p = 0; p < 8; ++p) H[lane * 8 + p] = 0;
#pragma unroll
        for (int it = 0; it < 64; ++it) {
            unsigned int t9 = key[it] - base;
            unsigned int b0 = t9 >> 19; if (b0 > 1023u) b0 = 1023u;
            if (b0 == P) atomicAdd(&H[(t9 >> 10) & 511], 1);
        }
        wave_scan_find<8>(H, rem, lane, B, below, hB);
        P = (P << 9) | (unsigned int)B;
        rem -= below;
        S = 10;
        if (hB != rem) {
#pragma unroll
            for (int p = 0; p < 8; ++p) H[lane * 8 + p] = 0;
#pragma unroll
            for (int it = 0; it < 64; ++it) {
                unsigned int t9 = key[it] - base;
                if ((t9 >> 10) == P) atomicAdd(&H[(t9 >> 1) & 511], 1);
            }
            wave_scan_find<8>(H, rem, lane, B, below, hB);
            P = (P << 9) | (unsigned int)B;
            rem -= below;
            S = 1;
        }
    }
    // compact: v < P always taken; v == P first `rem` taken (19 total + self)
    int* OC = cnts[wv];
#pragma unroll
    for (int it = 0; it < 64; ++it) {
        unsigned int t9 = key[it] - base;
        unsigned int v;
        if (S == 19) { v = t9 >> 19; if (v > 1023u) v = 1023u; }
        else v = t9 >> S;
        if (v <= P) {
            bool take = v < P;
            if (!take) { int e = atomicAdd(&OC[1], 1); take = (e < rem); }
            if (take) { int pos = atomicAdd(&OC[0], 1); outi[wv][pos] = it * 64 + lane; }
        }
    }
    if (lane == 0) outi[wv][KNN - 1] = q;
    const int obase = (b * NPTS + q) * KNN;
    if (lane < KNN) idx[obase + lane] = outi[wv][lane];
    // fused edge moments for bn1
    float st[27];
#pragma unroll
    for (int v = 0; v < 27; ++v) st[v] = 0.f;
    if (lane < KNN) {
        int j = outi[wv][lane];
        float e[6];
        e[0] = qx; e[1] = qy; e[2] = qz;
        e[3] = px[j] - qx; e[4] = py[j] - qy; e[5] = pz[j] - qz;
        int id = 6;
#pragma unroll
        for (int i = 0; i < 6; ++i) {
            st[i] = e[i];
#pragma unroll
            for (int jj = i; jj < 6; ++jj) { st[id] = e[i] * e[jj]; id++; }
        }
    }
#pragma unroll
    for (int v = 0; v < 27; ++v) {
        float s = st[v];
        s += __shfl_xor(s, 32); s += __shfl_xor(s, 16); s += __shfl_xor(s, 8);
        s += __shfl_xor(s, 4);  s += __shfl_xor(s, 2);  s += __shfl_xor(s, 1);
        st[v] = s;
    }
    if (lane == 0) {
#pragma unroll
        for (int v = 0; v < 27; ++v) atomicAdd(&estat[v], st[v]);
    }
    __syncthreads();
    if (tid < 27) atomicAdd(&W[OFF_ES + (blockIdx.x & 31) * 32 + tid], estat[tid]);
}

// bn1 affine from edge moments
__global__ void k_fin1(const float* __restrict__ w1, const float* __restrict__ g1,
                       const float* __restrict__ b1, float* W) {
    __shared__ float es[27];
    const int c = threadIdx.x;
    if (c < 27) {
        float s = 0.f;
        for (int p = 0; p < 32; ++p) s += W[OFF_ES + p * 32 + c];
        es[c] = s;
    }
    __syncthreads();
    float wr[6];
#pragma unroll
    for (int i = 0; i < 6; ++i) wr[i] = w1[c * 6 + i];
    float m = 0.f;
#pragma unroll
    for (int i = 0; i < 6; ++i) m += wr[i] * es[i];
    m *= (1.f / CNT1f);
    float qv = 0.f;
    int id = 6;
#pragma unroll
    for (int i = 0; i < 6; ++i)
#pragma unroll
        for (int jj = 0; jj < 6; ++jj)
            if (jj >= i) { qv += (jj == i ? 1.f : 2.f) * wr[i] * wr[jj] * es[id]; id++; }
    qv *= (1.f / CNT1f);
    float var = qv - m * m;
    float sc = g1[c] * rsqrtf(var + BNEPS);
    W[OFF_SC1 + c] = sc;
    W[OFF_SH1 + c] = b1[c] - m * sc;
}

// -------- gram1 (MFMA): G1 = Sum(h1 h1^T), S1 via appended ones-row ---------
__global__ __launch_bounds__(256) void k_gram1(const float* __restrict__ x, const int* __restrict__ idx,
                                               const float* __restrict__ w1, float* W) {
    __shared__ unsigned short h1t[80 * 136];   // 21760 B
    __shared__ float eds[128 * 6];
    __shared__ float w1s[64 * 6];
    __shared__ float sc1s[64], sh1s[64];
    const int t = threadIdx.x;
    const int b = blockIdx.x >> 6;                 // 64 blocks per batch
    const int ebase_b = (blockIdx.x & 63) * 1280;  // edges within batch
    const float* xb = x + b * 3 * NPTS;
    if (t < 384) w1s[t] = w1[t];
    if (t < 64) { sc1s[t] = W[OFF_SC1 + t]; sh1s[t] = W[OFF_SH1 + t]; }
    for (int i = t; i < 2048; i += 256) {          // rows 64..79
        int rr = i >> 7, e = i & 127;
        h1t[(64 + rr) * 136 + e] = (rr == 0) ? (unsigned short)0x3F80 : (unsigned short)0;
    }
    const int w = t >> 6, lane = t & 63, n16 = lane & 15, quad = lane >> 4;
    f32x4 acc[5];
#pragma unroll
    for (int j = 0; j < 5; ++j) acc[j] = (f32x4){0.f, 0.f, 0.f, 0.f};
    for (int ck = 0; ck < 10; ++ck) {
        __syncthreads();
        if (t < 128) {   // stage 128 edges
            int e_l = ebase_b + ck * 128 + t;
            int q = e_l / KNN;
            int jn = idx[b * (NPTS * KNN) + e_l];
            float cx = xb[q], cy = xb[NPTS + q], cz = xb[2 * NPTS + q];
            float* E = &eds[t * 6];
            E[0] = cx; E[1] = cy; E[2] = cz;
            E[3] = xb[jn] - cx; E[4] = xb[NPTS + jn] - cy; E[5] = xb[2 * NPTS + jn] - cz;
        }
        __syncthreads();
        {   // h1 rows 0..63
            const int e128 = t & 127, half = t >> 7;
            float e0 = eds[e128 * 6 + 0], e1 = eds[e128 * 6 + 1], e2 = eds[e128 * 6 + 2];
            float e3 = eds[e128 * 6 + 3], e4 = eds[e128 * 6 + 4], e5 = eds[e128 * 6 + 5];
#pragma unroll 4
            for (int cc = 0; cc < 32; ++cc) {
                int c = half * 32 + cc;
                const float* wr = &w1s[c * 6];
                float z = wr[0] * e0 + wr[1] * e1 + wr[2] * e2 + wr[3] * e3 + wr[4] * e4 + wr[5] * e5;
                float h = sc1s[c] * z + sh1s[c];
                h1t[c * 136 + e128] = f2bf(h > 0.f ? h : 0.f);
            }
        }
        __syncthreads();
#pragma unroll
        for (int ks = 0; ks < 4; ++ks) {
            s16x8 Af = *(const s16x8*)&h1t[(w * 16 + n16) * 136 + ks * 32 + quad * 8];
#pragma unroll
            for (int jt = 0; jt < 5; ++jt) {
                s16x8 Bf = *(const s16x8*)&h1t[(jt * 16 + n16) * 136 + ks * 32 + quad * 8];
                acc[jt] = __builtin_amdgcn_mfma_f32_16x16x32_bf16(Af, Bf, acc[jt], 0, 0, 0);
            }
        }
    }
    const int part = blockIdx.x & 3;
    const int gi = w * 16 + quad * 4;
#pragma unroll
    for (int jt = 0; jt < 4; ++jt)
#pragma unroll
        for (int r = 0; r < 4; ++r)
            atomicAdd(&W[OFF_G1P + part * 4096 + (gi + r) * 64 + jt * 16 + n16], acc[jt][r]);
    if (n16 == 0) {
#pragma unroll
        for (int r = 0; r < 4; ++r)
            atomicAdd(&W[OFF_S1P + part * 64 + gi + r], acc[4][r]);
    }
}

// bn2 affine from Gram
__global__ __launch_bounds__(256) void k_fin2(const float* __restrict__ w2, const float* __restrict__ g2,
                                              const float* __restrict__ b2, float* W) {
    __shared__ float Gs[4096];
    __shared__ float s1s[64];
    __shared__ float w2s[128 * 65];
    const int t = threadIdx.x;
    for (int i = t; i < 4096; i += 256)
        Gs[i] = W[OFF_G1P + i] + W[OFF_G1P + 4096 + i] + W[OFF_G1P + 8192 + i] + W[OFF_G1P + 12288 + i];
    if (t < 64) s1s[t] = W[OFF_S1P + t] + W[OFF_S1P + 64 + t] + W[OFF_S1P + 128 + t] + W[OFF_S1P + 192 + t];
    for (int i = t; i < 8192; i += 256) w2s[(i >> 6) * 65 + (i & 63)] = w2[i];
    __syncthreads();
    const int c = t >> 1, half = t & 1;
    float acc = 0.f;
    for (int ii = 0; ii < 32; ++ii) {
        int i = 32 * half + ii;
        float wi = w2s[c * 65 + i];
        float inner = 0.f;
        for (int j = 0; j < 64; ++j) inner += Gs[i * 64 + j] * w2s[c * 65 + j];
        acc += wi * inner;
    }
    acc += __shfl_xor(acc, 1);
    if (half == 0) {
        float ms = 0.f;
        for (int j = 0; j < 64; ++j) ms += w2s[c * 65 + j] * s1s[j];
        float mean = ms * (1.f / CNT1f);
        float var = acc * (1.f / CNT1f) - mean * mean;
        float sc = g2[c] * rsqrtf(var + BNEPS);
        W[OFF_SC2 + c] = sc;
        W[OFF_SH2 + c] = b2[c] - mean * sc;
    }
}

// -------- c2apply (MFMA): conv1+bn1+relu -> conv2 -> bn2+relu -> maxK -> M --
// w2 B-fragments loaded directly from pre-converted global bf16 (L2-cached).
__global__ __launch_bounds__(256) void k_c2apply(const float* __restrict__ x, const int* __restrict__ idx,
                                                 const float* __restrict__ w1, float* W) {
    __shared__ unsigned short h1b[128 * 72];   // [row=q*32+kk][k=64 chans of h1]
    __shared__ float eds[80 * 6];
    const int t = threadIdx.x;
    const int b = blockIdx.y, q0 = blockIdx.x * 4;
    const float* xb = x + b * 3 * NPTS;
    const int ebase = (b * NPTS + q0) * KNN;
    const unsigned short* w2b = (const unsigned short*)(W + OFF_W2B);
    if (t < 80) {
        int q = q0 + t / KNN;
        int jn = idx[ebase + t];
        float cx = xb[q], cy = xb[NPTS + q], cz = xb[2 * NPTS + q];
        float* E = &eds[t * 6];
        E[0] = cx; E[1] = cy; E[2] = cz;
        E[3] = xb[jn] - cx; E[4] = xb[NPTS + jn] - cy; E[5] = xb[2 * NPTS + jn] - cz;
    }
    __syncthreads();
    {   // h1: thread (chan j64, query grp); pad rows 20..31 with zeros
        const int j64 = t & 63, grp = t >> 6;
        float wr[6];
#pragma unroll
        for (int i = 0; i < 6; ++i) wr[i] = w1[j64 * 6 + i];
        const float sc = W[OFF_SC1 + j64], sh = W[OFF_SH1 + j64];
#pragma unroll 4
        for (int kk = 0; kk < 32; ++kk) {
            float v = 0.f;
            if (kk < 20) {
                const float* E = &eds[(grp * 20 + kk) * 6];
                float z = wr[0] * E[0] + wr[1] * E[1] + wr[2] * E[2] + wr[3] * E[3] + wr[4] * E[4] + wr[5] * E[5];
                float h = sc * z + sh;
                v = h > 0.f ? h : 0.f;
            }
            h1b[(grp * 32 + kk) * 72 + j64] = f2bf(v);
        }
    }
    __syncthreads();
    const int w = t >> 6, lane = t & 63, n16 = lane & 15, quad = lane >> 4;
    unsigned short* Mb = (unsigned short*)(W + OFF_M);
#pragma unroll
    for (int nt_i = 0; nt_i < 2; ++nt_i) {
        const int nt = 2 * w + nt_i;
        const int chan = nt * 16 + n16;
        const float sc2 = W[OFF_SC2 + chan], sh2 = W[OFF_SH2 + chan];
        s16x8 Bf0 = *(const s16x8*)&w2b[chan * 64 + quad * 8];
        s16x8 Bf1 = *(const s16x8*)&w2b[chan * 64 + 32 + quad * 8];
#pragma unroll
        for (int q = 0; q < 4; ++q) {
            f32x4 accA = (f32x4){0.f, 0.f, 0.f, 0.f};
            f32x4 accB = (f32x4){0.f, 0.f, 0.f, 0.f};
            s16x8 a0 = *(const s16x8*)&h1b[(q * 32 + n16) * 72 + quad * 8];
            s16x8 a1 = *(const s16x8*)&h1b[(q * 32 + 16 + n16) * 72 + quad * 8];
            accA = __builtin_amdgcn_mfma_f32_16x16x32_bf16(a0, Bf0, accA, 0, 0, 0);
            accB = __builtin_amdgcn_mfma_f32_16x16x32_bf16(a1, Bf0, accB, 0, 0, 0);
            a0 = *(const s16x8*)&h1b[(q * 32 + n16) * 72 + 32 + quad * 8];
            a1 = *(const s16x8*)&h1b[(q * 32 + 16 + n16) * 72 + 32 + quad * 8];
            accA = __builtin_amdgcn_mfma_f32_16x16x32_bf16(a0, Bf1, accA, 0, 0, 0);
            accB = __builtin_amdgcn_mfma_f32_16x16x32_bf16(a1, Bf1, accB, 0, 0, 0);
            float mx = 0.f;
#pragma unroll
            for (int r = 0; r < 4; ++r) {
                float h = sc2 * accA[r] + sh2;
                mx = fmaxf(mx, h > 0.f ? h : 0.f);
            }
            if (quad == 0) {   // kk = 16..19 valid only in quad 0
#pragma unroll
                for (int r = 0; r < 4; ++r) {
                    float h = sc2 * accB[r] + sh2;
                    mx = fmaxf(mx, h > 0.f ? h : 0.f);
                }
            }
            mx = fmaxf(mx, __shfl_xor(mx, 16));
            mx = fmaxf(mx, __shfl_xor(mx, 32));
            if (quad == 0)
                Mb[(b * NPTS + q0 + q) * 128 + chan] = f2bf(mx);
        }
    }
}

// -------- G3 = M^T M (128x128) and Sum(m) for bn3 (M is bf16) ---------------
__global__ __launch_bounds__(256) void k_gram3(float* W) {
    __shared__ float Ms[64 * 132];
    const int t = threadIdx.x;
    const int rg = t & 15, cg = t >> 4;
    const int r0 = blockIdx.x * 512;
    const unsigned int* Msrc = (const unsigned int*)(W + OFF_M);
    float acc[8][8];
#pragma unroll
    for (int i = 0; i < 8; ++i)
#pragma unroll
        for (int j = 0; j < 8; ++j) acc[i][j] = 0.f;
    float smacc = 0.f;
    for (int ch = 0; ch < 8; ++ch) {
        __syncthreads();
        for (int i = t; i < 4096; i += 256) {
            unsigned int v = Msrc[(r0 + ch * 64) * 64 + i];
            int row = i >> 6, c2 = i & 63;
            Ms[row * 132 + 2 * c2]     = __uint_as_float(v << 16);
            Ms[row * 132 + 2 * c2 + 1] = __uint_as_float(v & 0xFFFF0000u);
        }
        __syncthreads();
#pragma unroll 2
        for (int e = 0; e < 64; ++e) {
            float4 x0 = *(const float4*)&Ms[e * 132 + 8 * rg];
            float4 x1 = *(const float4*)&Ms[e * 132 + 8 * rg + 4];
            float4 y0 = *(const float4*)&Ms[e * 132 + 8 * cg];
            float4 y1 = *(const float4*)&Ms[e * 132 + 8 * cg + 4];
            float av[8] = {x0.x, x0.y, x0.z, x0.w, x1.x, x1.y, x1.z, x1.w};
            float bv[8] = {y0.x, y0.y, y0.z, y0.w, y1.x, y1.y, y1.z, y1.w};
#pragma unroll
            for (int i = 0; i < 8; ++i)
#pragma unroll
                for (int j = 0; j < 8; ++j) acc[i][j] += av[i] * bv[j];
        }
        if (t < 128) {
            float s = 0.f;
            for (int e = 0; e < 64; ++e) s += Ms[e * 132 + t];
            smacc += s;
        }
    }
    const int part = blockIdx.x & 1;
    float* Gp = &W[OFF_G3P + part * 16384];
#pragma unroll
    for (int i = 0; i < 8; ++i)
#pragma unroll
        for (int j = 0; j < 8; ++j)
            atomicAdd(&Gp[(8 * rg + i) * 128 + 8 * cg + j], acc[i][j]);
    if (t < 128) atomicAdd(&W[OFF_SM3P + part * 128 + t], smacc);
}

// bn3 affine: 16 channels per block
__global__ __launch_bounds__(256) void k_fin3(const float* __restrict__ w3, const float* __restrict__ g3,
                                              const float* __restrict__ b3, float* W) {
    __shared__ float G3s[128 * 129];
    __shared__ float w3s[16 * 132];
    __shared__ float sm3[128];
    __shared__ float red[256];
    __shared__ float mred[16];
    const int t = threadIdx.x;
    const int c0 = blockIdx.x * 16;
    for (int i = t; i < 16384; i += 256)
        G3s[(i >> 7) * 129 + (i & 127)] = W[OFF_G3P + i] + W[OFF_G3P + 16384 + i];
    for (int i = t; i < 2048; i += 256)
        w3s[(i >> 7) * 132 + (i & 127)] = w3[(c0 + (i >> 7)) * 128 + (i & 127)];
    if (t < 128) sm3[t] = W[OFF_SM3P + t] + W[OFF_SM3P + 128 + t];
    __syncthreads();
    const int cl = t >> 4, seg = t & 15;
    float acc = 0.f;
    for (int ii = 0; ii < 8; ++ii) {
        int i = 8 * seg + ii;
        float wi = w3s[cl * 132 + i];
        float inner = 0.f;
        for (int j = 0; j < 128; ++j) inner += G3s[i * 129 + j] * w3s[cl * 132 + j];
        acc += wi * inner;
    }
    red[t] = acc;
    if (seg == 0) {
        float ms = 0.f;
        for (int j = 0; j < 128; ++j) ms += w3s[cl * 132 + j] * sm3[j];
        mred[cl] = ms;
    }
    __syncthreads();
    if (t < 16) {
        float s = 0.f;
#pragma unroll
        for (int k = 0; k < 16; ++k) s += red[t * 16 + k];
        float mean = mred[t] * (1.f / CNT3f);
        float var = s * (1.f / CNT3f) - mean * mean;
        float sc = g3[c0 + t] * rsqrtf(var + BNEPS);
        W[OFF_SC3 + c0 + t] = sc;
        W[OFF_SH3 + c0 + t] = b3[c0 + t] - mean * sc;
    }
}

// -------- conv3 (MFMA): z3 = M @ w3^T, bn3+relu, max over rows -> GMAX ------
// w3 B-fragments loaded directly from pre-converted global bf16 (L2-cached).
__global__ __launch_bounds__(256) void k_conv3(float* W) {
    __shared__ unsigned short Mt[64 * 136];     // 64 rows x K=128
    const int t = threadIdx.x;
    const int p0 = blockIdx.x * 64, c0g = blockIdx.y * 128;
    const unsigned int* Msrc = (const unsigned int*)(W + OFF_M);
    const unsigned short* w3b = (const unsigned short*)(W + OFF_W3B);
    for (int i = t; i < 4096; i += 256) {
        int row = i >> 6, c2 = i & 63;
        *(unsigned int*)&Mt[row * 136 + 2 * c2] = Msrc[(p0 + row) * 64 + c2];
    }
    __syncthreads();
    const int w = t >> 6, lane = t & 63, n16 = lane & 15, quad = lane >> 4;
    const int bbatch = p0 >> 12;
#pragma unroll
    for (int nt_i = 0; nt_i < 2; ++nt_i) {
        const int nt = 2 * w + nt_i;
        const int chan = c0g + nt * 16 + n16;
        const float sc3 = W[OFF_SC3 + chan], sh3 = W[OFF_SH3 + chan];
        s16x8 Bf[4];
#pragma unroll
        for (int ks = 0; ks < 4; ++ks)
            Bf[ks] = *(const s16x8*)&w3b[chan * 128 + ks * 32 + quad * 8];
        float mx = 0.f;
#pragma unroll
        for (int mt = 0; mt < 4; ++mt) {
            f32x4 acc = (f32x4){0.f, 0.f, 0.f, 0.f};
#pragma unroll
            for (int ks = 0; ks < 4; ++ks) {
                s16x8 Af = *(const s16x8*)&Mt[(mt * 16 + n16) * 136 + ks * 32 + quad * 8];
                acc = __builtin_amdgcn_mfma_f32_16x16x32_bf16(Af, Bf[ks], acc, 0, 0, 0);
            }
#pragma unroll
            for (int r = 0; r < 4; ++r) {
                float h = sc3 * acc[r] + sh3;
                mx = fmaxf(mx, h > 0.f ? h : 0.f);
            }
        }
        mx = fmaxf(mx, __shfl_xor(mx, 16));
        mx = fmaxf(mx, __shfl_xor(mx, 32));
        if (quad == 0)
            atomicMax((unsigned int*)&W[OFF_GMAX + bbatch * 1024 + chan], __float_as_uint(mx));
    }
}

// -------- z4 = gmax(8x1024) @ w4^T(512x1024) --------------------------------
__global__ __launch_bounds__(256) void k_fc4(const float* __restrict__ w4, float* W) {
    __shared__ float red[256];
    const int t = threadIdx.x;
    const int oidx = t >> 3, s = t & 7;
    const int cc = oidx >> 3, b = oidx & 7;
    const int c = blockIdx.x * 4 + cc;
    const float* g = &W[OFF_GMAX];
    const float* wr = &w4[c * 1024 + s * 128];
    const float* gr = &g[b * 1024 + s * 128];
    float p = 0.f;
    for (int j = 0; j < 128; ++j) p += wr[j] * gr[j];
    red[t] = p;
    __syncthreads();
    if (t < 32) {
        float tot = 0.f;
        for (int k = 0; k < 8; ++k) tot += red[t * 8 + k];
        W[OFF_Z4 + (t & 7) * 512 + blockIdx.x * 4 + (t >> 3)] = tot;
    }
}

// -------- tail: bn4+relu, fc5, bn5+relu, final linear + eye -----------------
__global__ __launch_bounds__(512) void k_tail(const float* __restrict__ g4, const float* __restrict__ b4,
                                              const float* __restrict__ w5, const float* __restrict__ g5,
                                              const float* __restrict__ b5, const float* __restrict__ wl,
                                              const float* __restrict__ bl, float* W, float* __restrict__ out) {
    __shared__ float h4L[8 * 512];
    __shared__ float w5s[2 * 256 * 9];
    __shared__ float zp[2 * 2048];
    const int t = threadIdx.x;
    {
        float v[8]; float s = 0.f, q = 0.f;
#pragma unroll
        for (int b = 0; b < 8; ++b) { v[b] = W[OFF_Z4 + b * 512 + t]; s += v[b]; q += v[b] * v[b]; }
        float mean = s * 0.125f;
        float var = q * 0.125f - mean * mean;
        float sc = g4[t] * rsqrtf(var + BNEPS);
        float sh = b4[t] - mean * sc;
#pragma unroll
        for (int b = 0; b < 8; ++b) {
            float h = sc * v[b] + sh;
            h4L[b * 512 + t] = h > 0.f ? h : 0.f;
        }
    }
    const int c5 = t & 255, half = t >> 8;
    float acc[8];
#pragma unroll
    for (int b = 0; b < 8; ++b) acc[b] = 0.f;
    for (int jt = 0; jt < 32; ++jt) {
        __syncthreads();
        for (int i = t; i < 4096; i += 512) {
            int h = i >> 11, rem = i & 2047;
            int ci = rem >> 3, jj = rem & 7;
            w5s[h * 2304 + ci * 9 + jj] = w5[ci * 512 + h * 256 + jt * 8 + jj];
        }
        __syncthreads();
#pragma unroll
        for (int jj = 0; jj < 8; ++jj) {
            float wv = w5s[half * 2304 + c5 * 9 + jj];
            int jg = half * 256 + jt * 8 + jj;
#pragma unroll
            for (int b = 0; b < 8; ++b) acc[b] += wv * h4L[b * 512 + jg];
        }
    }
#pragma unroll
    for (int b = 0; b < 8; ++b) zp[half * 2048 + b * 256 + c5] = acc[b];
    __syncthreads();
    if (t < 256) {
        float v[8], s = 0.f, q = 0.f;
#pragma unroll
        for (int b = 0; b < 8; ++b) {
            v[b] = zp[b * 256 + t] + zp[2048 + b * 256 + t];
            s += v[b]; q += v[b] * v[b];
        }
        float mean = s * 0.125f, var = q * 0.125f - mean * mean;
        float sc = g5[t] * rsqrtf(var + BNEPS), sh = b5[t] - mean * sc;
#pragma unroll
        for (int b = 0; b < 8; ++b) { float h = sc * v[b] + sh; zp[b * 256 + t] = h > 0.f ? h : 0.f; }
    }
    __syncthreads();
    if (t < 72) {
        int b = t / 9, r = t % 9;
        float a = bl[r] + ((r == 0 || r == 4 || r == 8) ? 1.f : 0.f);
        for (int j = 0; j < 256; ++j) a += wl[r * 256 + j] * zp[b * 256 + j];
        out[b * 9 + r] = a;
    }
}

extern "C" void kernel_launch(void* const* d_in, const int* in_sizes, int n_in,
                              void* d_out, int out_size, void* d_ws, size_t ws_size,
                              hipStream_t stream) {
    const float* x  = (const float*)d_in[0];
    const float* w1 = (const float*)d_in[1];
    const float* g1 = (const float*)d_in[2];
    const float* b1 = (const float*)d_in[3];
    const float* w2 = (const float*)d_in[4];
    const float* g2 = (const float*)d_in[5];
    const float* b2 = (const float*)d_in[6];
    const float* w3 = (const float*)d_in[7];
    const float* g3 = (const float*)d_in[8];
    const float* b3 = (const float*)d_in[9];
    const float* w4 = (const float*)d_in[10];
    const float* g4 = (const float*)d_in[11];
    const float* b4 = (const float*)d_in[12];
    const float* w5 = (const float*)d_in[13];
    const float* g5 = (const float*)d_in[14];
    const float* b5 = (const float*)d_in[15];
    const float* wl = (const float*)d_in[16];
    const float* bl = (const float*)d_in[17];
    float* W = (float*)d_ws;
    int* idx = (int*)d_ws;
    float* out = (float*)d_out;

    k_init<<<dim3(69), dim3(256), 0, stream>>>(W, ZERO1_BEG, ZERO1_CNT);
    k_prep<<<dim3(512), dim3(256), 0, stream>>>(w2, w3, W);
    k_knn<<<dim3(1024, 8), dim3(256), 0, stream>>>(x, idx, W);
    k_fin1<<<dim3(1), dim3(64), 0, stream>>>(w1, g1, b1, W);
    k_gram1<<<dim3(512), dim3(256), 0, stream>>>(x, idx, w1, W);
    k_fin2<<<dim3(1), dim3(256), 0, stream>>>(w2, g2, b2, W);
    k_c2apply<<<dim3(1024, 8), dim3(256), 0, stream>>>(x, idx, w1, W);
    k_init<<<dim3(161), dim3(256), 0, stream>>>(W, ZERO2_BEG, ZERO2_CNT);
    k_gram3<<<dim3(64), dim3(256), 0, stream>>>(W);
    k_fin3<<<dim3(64), dim3(256), 0, stream>>>(w3, g3, b3, W);
    k_conv3<<<dim3(512, 8), dim3(256), 0, stream>>>(W);
    k_fc4<<<dim3(128), dim3(256), 0, stream>>>(w4, W);
    k_tail<<<dim3(1), dim3(512), 0, stream>>>(g4, b4, w5, g5, b5, wl, bl, W, out);
}